// Round 1
// baseline (2723.321 us; speedup 1.0000x reference)
//
#include <hip/hip_runtime.h>
#include <math.h>

// Problem constants
#define HW 4096      // 64*64
#define NB 8         // batch

// ws layout in floats (~105.3 MB total; d_ws assumed >= this)
#define WS_B123  0ull          // [8][384][4096]  b1 | b2i | b3i
#define WS_B4    12582912ull   // [8][128][4096]
#define WS_B2    16777216ull   // [8][128][4096]  deform3x3 out
#define WS_B3    20971520ull   // [8][128][4096]  deform5x5 out
#define WS_OFF2  25165824ull   // [8][18][4096]
#define WS_OFF3  25755648ull   // [8][50][4096]
#define WS_WPACK 27394048ull   // [384][512]
#define WS_BPACK 27590656ull   // [384]

// ---------------------------------------------------------------- pack weights
__global__ void k_pack(const float* __restrict__ w1, const float* __restrict__ w21,
                       const float* __restrict__ w31, const float* __restrict__ b1,
                       const float* __restrict__ b21, const float* __restrict__ b31,
                       float* __restrict__ wp, float* __restrict__ bp) {
    int i = blockIdx.x * 256 + threadIdx.x;
    if (i < 384 * 512) {
        int o = i >> 9;
        float v;
        if (o < 128)      v = w1[i];
        else if (o < 256) v = w21[i - 128 * 512];
        else              v = w31[i - 256 * 512];
        wp[i] = v;
    }
    if (i < 384)
        bp[i] = (i < 128) ? b1[i] : (i < 256) ? b21[i - 128] : b31[i - 256];
}

// ------------------------------------------------- 1x1 conv GEMM: out = W @ in
// W: [M][512] row-major, In: [B][512][HW], Out: [B][M][HW]. Tile 128x128, BK=16.
__global__ __launch_bounds__(256) void k_gemm1x1(
        const float* __restrict__ Wm, const float* __restrict__ bias,
        const float* __restrict__ In, float* __restrict__ Out, int M) {
    __shared__ float sA[16][128];
    __shared__ float sB[16][128];
    const int tid = threadIdx.x;
    const int p0 = blockIdx.x * 128;
    const int o0 = blockIdx.y * 128;
    const int b  = blockIdx.z;
    const float* inb = In + (size_t)b * 512 * HW;

    const int aO = tid & 127;
    const int aK = (tid >> 7) << 3;     // 0 or 8
    const int bK = tid >> 4;            // 0..15
    const int bP = (tid & 15) << 3;     // 0..120
    const int ot = (tid >> 4) << 3;
    const int pt = (tid & 15) << 3;

    float acc[8][8] = {};

    for (int k0 = 0; k0 < 512; k0 += 16) {
        const float* wrow = Wm + (size_t)(o0 + aO) * 512 + k0 + aK;
        float4 a0 = *(const float4*)(wrow);
        float4 a1 = *(const float4*)(wrow + 4);
        const float* src = inb + (size_t)(k0 + bK) * HW + p0 + bP;
        float4 b0 = *(const float4*)(src);
        float4 b1 = *(const float4*)(src + 4);
        __syncthreads();
        sA[aK + 0][aO] = a0.x; sA[aK + 1][aO] = a0.y;
        sA[aK + 2][aO] = a0.z; sA[aK + 3][aO] = a0.w;
        sA[aK + 4][aO] = a1.x; sA[aK + 5][aO] = a1.y;
        sA[aK + 6][aO] = a1.z; sA[aK + 7][aO] = a1.w;
        *(float4*)&sB[bK][bP]     = b0;
        *(float4*)&sB[bK][bP + 4] = b1;
        __syncthreads();
        #pragma unroll
        for (int kk = 0; kk < 16; ++kk) {
            float4 x0 = *(float4*)&sA[kk][ot];
            float4 x1 = *(float4*)&sA[kk][ot + 4];
            float4 y0 = *(float4*)&sB[kk][pt];
            float4 y1 = *(float4*)&sB[kk][pt + 4];
            float av[8] = {x0.x, x0.y, x0.z, x0.w, x1.x, x1.y, x1.z, x1.w};
            float bv[8] = {y0.x, y0.y, y0.z, y0.w, y1.x, y1.y, y1.z, y1.w};
            #pragma unroll
            for (int i = 0; i < 8; ++i)
                #pragma unroll
                for (int j = 0; j < 8; ++j)
                    acc[i][j] += av[i] * bv[j];
        }
    }
    #pragma unroll
    for (int i = 0; i < 8; ++i) {
        int o = o0 + ot + i;
        float bs = bias[o];
        float* dst = Out + ((size_t)b * M + o) * HW + p0 + pt;
        float4 r0 = {acc[i][0] + bs, acc[i][1] + bs, acc[i][2] + bs, acc[i][3] + bs};
        float4 r1 = {acc[i][4] + bs, acc[i][5] + bs, acc[i][6] + bs, acc[i][7] + bs};
        *(float4*)dst = r0;
        *(float4*)(dst + 4) = r1;
    }
}

// -------------------------------------- b4 GEMM with fused 3x3 maxpool staging
// grid (32,1,8). p-tile 128 = rows h0,h0+1. tmp holds rows h0-1..h0+2 per c-chunk.
__global__ __launch_bounds__(256) void k_gemm_b4(
        const float* __restrict__ Wm, const float* __restrict__ bias,
        const float* __restrict__ X, float* __restrict__ Out) {
    __shared__ float sA[16][128];
    __shared__ float sB[16][128];
    __shared__ float tmp[16][4][64];
    const int tid = threadIdx.x;
    const int p0 = blockIdx.x * 128;
    const int h0 = blockIdx.x * 2;
    const int b  = blockIdx.z;
    const float* xb = X + (size_t)b * 512 * HW;

    const int aO = tid & 127;
    const int aK = (tid >> 7) << 3;
    const int bK = tid >> 4;
    const int bP = (tid & 15) << 3;
    const int ot = (tid >> 4) << 3;
    const int pt = (tid & 15) << 3;
    const int tC = tid >> 4;
    const int tBase = (tid & 15) << 4;

    float acc[8][8] = {};

    for (int k0 = 0; k0 < 512; k0 += 16) {
        const float* wrow = Wm + (size_t)aO * 512 + k0 + aK;
        float4 a0 = *(const float4*)(wrow);
        float4 a1 = *(const float4*)(wrow + 4);
        float4 t4[4];
        #pragma unroll
        for (int i = 0; i < 4; ++i) {
            int rw = tBase + i * 4;
            int r = rw >> 6, w = rw & 63;
            int hh = h0 - 1 + r;
            if (hh >= 0 && hh < 64)
                t4[i] = *(const float4*)(xb + (size_t)(k0 + tC) * HW + hh * 64 + w);
            else
                t4[i] = make_float4(-INFINITY, -INFINITY, -INFINITY, -INFINITY);
        }
        __syncthreads();
        sA[aK + 0][aO] = a0.x; sA[aK + 1][aO] = a0.y;
        sA[aK + 2][aO] = a0.z; sA[aK + 3][aO] = a0.w;
        sA[aK + 4][aO] = a1.x; sA[aK + 5][aO] = a1.y;
        sA[aK + 6][aO] = a1.z; sA[aK + 7][aO] = a1.w;
        #pragma unroll
        for (int i = 0; i < 4; ++i) {
            int rw = tBase + i * 4;
            *(float4*)&tmp[tC][rw >> 6][rw & 63] = t4[i];
        }
        __syncthreads();
        float sv[8];
        #pragma unroll
        for (int pp = 0; pp < 8; ++pp) {
            int pos = bP + pp;
            int lr = pos >> 6, w = pos & 63;
            float m = -INFINITY;
            #pragma unroll
            for (int rr = 0; rr < 3; ++rr) {
                m = fmaxf(m, tmp[bK][lr + rr][w]);
                if (w > 0)  m = fmaxf(m, tmp[bK][lr + rr][w - 1]);
                if (w < 63) m = fmaxf(m, tmp[bK][lr + rr][w + 1]);
            }
            sv[pp] = m;
        }
        *(float4*)&sB[bK][bP]     = make_float4(sv[0], sv[1], sv[2], sv[3]);
        *(float4*)&sB[bK][bP + 4] = make_float4(sv[4], sv[5], sv[6], sv[7]);
        __syncthreads();
        #pragma unroll
        for (int kk = 0; kk < 16; ++kk) {
            float4 x0 = *(float4*)&sA[kk][ot];
            float4 x1 = *(float4*)&sA[kk][ot + 4];
            float4 y0 = *(float4*)&sB[kk][pt];
            float4 y1 = *(float4*)&sB[kk][pt + 4];
            float av[8] = {x0.x, x0.y, x0.z, x0.w, x1.x, x1.y, x1.z, x1.w};
            float bv[8] = {y0.x, y0.y, y0.z, y0.w, y1.x, y1.y, y1.z, y1.w};
            #pragma unroll
            for (int i = 0; i < 8; ++i)
                #pragma unroll
                for (int j = 0; j < 8; ++j)
                    acc[i][j] += av[i] * bv[j];
        }
    }
    #pragma unroll
    for (int i = 0; i < 8; ++i) {
        int o = ot + i;
        float bs = bias[o];
        float* dst = Out + ((size_t)b * 128 + o) * HW + p0 + pt;
        float4 r0 = {acc[i][0] + bs, acc[i][1] + bs, acc[i][2] + bs, acc[i][3] + bs};
        float4 r1 = {acc[i][4] + bs, acc[i][5] + bs, acc[i][6] + bs, acc[i][7] + bs};
        *(float4*)dst = r0;
        *(float4*)(dst + 4) = r1;
    }
}

// ------------------------------------------- small direct conv (offset convs)
// grid (4, OCH, 8); thread = 4 consecutive w outputs for one (b,o,h).
template<int KS, int OCH>
__global__ __launch_bounds__(256) void k_conv_small(
        const float* __restrict__ In, long inBStride,
        const float* __restrict__ Wt, const float* __restrict__ bias,
        float* __restrict__ Out) {
    constexpr int PAD = KS / 2;
    const int o = blockIdx.y;
    const int b = blockIdx.z;
    const int h = blockIdx.x * 16 + (threadIdx.x >> 4);
    const int w0 = (threadIdx.x & 15) << 2;
    const float* inb = In + (size_t)b * inBStride;
    const float* wo = Wt + (size_t)o * 128 * KS * KS;
    float bs = bias[o];
    float acc[4] = {bs, bs, bs, bs};
    for (int c = 0; c < 128; ++c) {
        const float* ip = inb + (size_t)c * HW;
        const float* wp = wo + c * KS * KS;
        float wreg[KS * KS];
        #pragma unroll
        for (int q = 0; q < KS * KS; ++q) wreg[q] = wp[q];
        #pragma unroll
        for (int ky = 0; ky < KS; ++ky) {
            int yy = h + ky - PAD;
            if (yy >= 0 && yy < 64) {
                const float* row = ip + yy * 64;
                float4 v0 = (w0 >= 4)  ? *(const float4*)(row + w0 - 4) : make_float4(0, 0, 0, 0);
                float4 v1 = *(const float4*)(row + w0);
                float4 v2 = (w0 <= 56) ? *(const float4*)(row + w0 + 4) : make_float4(0, 0, 0, 0);
                float wnd[12] = {v0.x, v0.y, v0.z, v0.w, v1.x, v1.y, v1.z, v1.w,
                                 v2.x, v2.y, v2.z, v2.w};
                #pragma unroll
                for (int kx = 0; kx < KS; ++kx) {
                    float wv = wreg[ky * KS + kx];
                    #pragma unroll
                    for (int i = 0; i < 4; ++i)
                        acc[i] += wnd[4 + i + kx - PAD] * wv;
                }
            }
        }
    }
    float* dst = Out + ((size_t)b * OCH + o) * HW + h * 64 + w0;
    *(float4*)dst = make_float4(acc[0], acc[1], acc[2], acc[3]);
}

// --------------------------------------------------------- deformable conv2d
// grid (64,1,8): one block per (b, output row). O=C=128.
template<int KS>
__global__ __launch_bounds__(256) void k_deform(
        const float* __restrict__ In, long inBStride,
        const float* __restrict__ Off,
        const float* __restrict__ Wt, const float* __restrict__ bias,
        float* __restrict__ Out) {
    constexpr int PAD = KS / 2;
    constexpr int TT = KS * KS;
    __shared__ float sW[16][128];
    __shared__ float sS[16][64];
    __shared__ float4 wts4[64];
    __shared__ int2 c01[64];
    const int tid = threadIdx.x;
    const int hrow = blockIdx.x;
    const int b = blockIdx.z;
    const float* inb = In + (size_t)b * inBStride;
    const float* offb = Off + (size_t)b * (2 * TT) * HW + hrow * 64;
    const int ot = (tid >> 4) << 3;
    const int pt = (tid & 15) << 2;
    const int sc = tid >> 4;
    const int sp = (tid & 15) << 2;
    float acc[8][4] = {};

    for (int t = 0; t < TT; ++t) {
        __syncthreads();
        if (tid < 64) {
            int w = tid;
            float dy = offb[(size_t)(2 * t) * HW + w];
            float dx = offb[(size_t)(2 * t + 1) * HW + w];
            float y = (float)(hrow + t / KS - PAD) + dy;
            float x = (float)(w + t % KS - PAD) + dx;
            float y0f = floorf(y), x0f = floorf(x);
            float wy = y - y0f, wx = x - x0f;
            wts4[w] = make_float4((1.f - wy) * (1.f - wx), (1.f - wy) * wx,
                                  wy * (1.f - wx), wy * wx);
            c01[w] = make_int2((int)y0f, (int)x0f);
        }
        __syncthreads();
        for (int c0 = 0; c0 < 128; c0 += 16) {
            float wv[8];
            #pragma unroll
            for (int i = 0; i < 8; ++i) {
                int lin = (tid << 3) + i;
                int kk = lin >> 7, oo = lin & 127;
                wv[i] = Wt[((size_t)oo * 128 + c0 + kk) * TT + t];
            }
            const float* imc = inb + (size_t)(c0 + sc) * HW;
            float sv[4];
            #pragma unroll
            for (int pp = 0; pp < 4; ++pp) {
                int pos = sp + pp;
                float4 wq = wts4[pos];
                int2 cc = c01[pos];
                int y0 = cc.x, x0 = cc.y;
                bool yv0 = (y0 >= 0) && (y0 < 64);
                bool yv1 = (y0 + 1 >= 0) && (y0 + 1 < 64);
                bool xv0 = (x0 >= 0) && (x0 < 64);
                bool xv1 = (x0 + 1 >= 0) && (x0 + 1 < 64);
                float v00 = (yv0 && xv0) ? imc[y0 * 64 + x0]           : 0.f;
                float v01 = (yv0 && xv1) ? imc[y0 * 64 + x0 + 1]       : 0.f;
                float v10 = (yv1 && xv0) ? imc[(y0 + 1) * 64 + x0]     : 0.f;
                float v11 = (yv1 && xv1) ? imc[(y0 + 1) * 64 + x0 + 1] : 0.f;
                sv[pp] = wq.x * v00 + wq.y * v01 + wq.z * v10 + wq.w * v11;
            }
            __syncthreads();
            #pragma unroll
            for (int i = 0; i < 8; ++i) {
                int lin = (tid << 3) + i;
                sW[lin >> 7][lin & 127] = wv[i];
            }
            *(float4*)&sS[sc][sp] = make_float4(sv[0], sv[1], sv[2], sv[3]);
            __syncthreads();
            #pragma unroll
            for (int kk = 0; kk < 16; ++kk) {
                float4 a0 = *(float4*)&sW[kk][ot];
                float4 a1 = *(float4*)&sW[kk][ot + 4];
                float4 bb = *(float4*)&sS[kk][pt];
                float av[8] = {a0.x, a0.y, a0.z, a0.w, a1.x, a1.y, a1.z, a1.w};
                float bv[4] = {bb.x, bb.y, bb.z, bb.w};
                #pragma unroll
                for (int i = 0; i < 8; ++i)
                    #pragma unroll
                    for (int j = 0; j < 4; ++j)
                        acc[i][j] += av[i] * bv[j];
            }
        }
    }
    #pragma unroll
    for (int i = 0; i < 8; ++i) {
        int o = ot + i;
        float bs = bias[o];
        float* dst = Out + ((size_t)b * 128 + o) * HW + hrow * 64 + pt;
        *(float4*)dst = make_float4(acc[i][0] + bs, acc[i][1] + bs,
                                    acc[i][2] + bs, acc[i][3] + bs);
    }
}

// -------------------------------------- final fuse: sigmoid(Wcc @ (cat*x)) + x
__global__ __launch_bounds__(256) void k_gemm_final(
        const float* __restrict__ Wm, const float* __restrict__ bias,
        const float* __restrict__ X,
        const float* __restrict__ B123, const float* __restrict__ B2,
        const float* __restrict__ B3, const float* __restrict__ B4,
        float* __restrict__ OutF) {
    __shared__ float sA[16][128];
    __shared__ float sB[16][128];
    const int tid = threadIdx.x;
    const int p0 = blockIdx.x * 128;
    const int o0 = blockIdx.y * 128;
    const int b  = blockIdx.z;
    const int aO = tid & 127;
    const int aK = (tid >> 7) << 3;
    const int bK = tid >> 4;
    const int bP = (tid & 15) << 3;
    const int ot = (tid >> 4) << 3;
    const int pt = (tid & 15) << 3;
    float acc[8][8] = {};

    for (int k0 = 0; k0 < 512; k0 += 16) {
        const float* wrow = Wm + (size_t)(o0 + aO) * 512 + k0 + aK;
        float4 a0 = *(const float4*)(wrow);
        float4 a1 = *(const float4*)(wrow + 4);
        int c = k0 + bK;
        const float* br;
        if (c < 128)      br = B123 + ((size_t)b * 384 + c) * HW;
        else if (c < 256) br = B2 + ((size_t)b * 128 + (c - 128)) * HW;
        else if (c < 384) br = B3 + ((size_t)b * 128 + (c - 256)) * HW;
        else              br = B4 + ((size_t)b * 128 + (c - 384)) * HW;
        const float* xr = X + ((size_t)b * 512 + c) * HW + p0 + bP;
        float4 u0 = *(const float4*)(br + p0 + bP);
        float4 u1 = *(const float4*)(br + p0 + bP + 4);
        float4 z0 = *(const float4*)(xr);
        float4 z1 = *(const float4*)(xr + 4);
        float4 m0 = {u0.x * z0.x, u0.y * z0.y, u0.z * z0.z, u0.w * z0.w};
        float4 m1 = {u1.x * z1.x, u1.y * z1.y, u1.z * z1.z, u1.w * z1.w};
        __syncthreads();
        sA[aK + 0][aO] = a0.x; sA[aK + 1][aO] = a0.y;
        sA[aK + 2][aO] = a0.z; sA[aK + 3][aO] = a0.w;
        sA[aK + 4][aO] = a1.x; sA[aK + 5][aO] = a1.y;
        sA[aK + 6][aO] = a1.z; sA[aK + 7][aO] = a1.w;
        *(float4*)&sB[bK][bP]     = m0;
        *(float4*)&sB[bK][bP + 4] = m1;
        __syncthreads();
        #pragma unroll
        for (int kk = 0; kk < 16; ++kk) {
            float4 x0 = *(float4*)&sA[kk][ot];
            float4 x1 = *(float4*)&sA[kk][ot + 4];
            float4 y0 = *(float4*)&sB[kk][pt];
            float4 y1 = *(float4*)&sB[kk][pt + 4];
            float av[8] = {x0.x, x0.y, x0.z, x0.w, x1.x, x1.y, x1.z, x1.w};
            float bv[8] = {y0.x, y0.y, y0.z, y0.w, y1.x, y1.y, y1.z, y1.w};
            #pragma unroll
            for (int i = 0; i < 8; ++i)
                #pragma unroll
                for (int j = 0; j < 8; ++j)
                    acc[i][j] += av[i] * bv[j];
        }
    }
    #pragma unroll
    for (int i = 0; i < 8; ++i) {
        int o = o0 + ot + i;
        float bs = bias[o];
        const float* xo = X + ((size_t)b * 512 + o) * HW + p0 + pt;
        float4 xv0 = *(const float4*)(xo);
        float4 xv1 = *(const float4*)(xo + 4);
        float r[8];
        #pragma unroll
        for (int j = 0; j < 8; ++j) {
            float f = acc[i][j] + bs;
            float sg = 1.f / (1.f + __expf(-f));
            float xv = (j < 4) ? ((const float*)&xv0)[j] : ((const float*)&xv1)[j - 4];
            r[j] = xv + sg;
        }
        float* dst = OutF + ((size_t)b * 512 + o) * HW + p0 + pt;
        *(float4*)dst = make_float4(r[0], r[1], r[2], r[3]);
        *(float4*)(dst + 4) = make_float4(r[4], r[5], r[6], r[7]);
    }
}

// ------------------------------------------------------------------- launcher
extern "C" void kernel_launch(void* const* d_in, const int* in_sizes, int n_in,
                              void* d_out, int out_size, void* d_ws, size_t ws_size,
                              hipStream_t stream) {
    const float* x      = (const float*)d_in[0];
    const float* w_b1   = (const float*)d_in[1];
    const float* b_b1   = (const float*)d_in[2];
    const float* w_b21  = (const float*)d_in[3];
    const float* b_b21  = (const float*)d_in[4];
    const float* w_off2 = (const float*)d_in[5];
    const float* b_off2 = (const float*)d_in[6];
    const float* w_ddc2 = (const float*)d_in[7];
    const float* b_ddc2 = (const float*)d_in[8];
    const float* w_b31  = (const float*)d_in[9];
    const float* b_b31  = (const float*)d_in[10];
    const float* w_off3 = (const float*)d_in[11];
    const float* b_off3 = (const float*)d_in[12];
    const float* w_ddc3 = (const float*)d_in[13];
    const float* b_ddc3 = (const float*)d_in[14];
    const float* w_b4   = (const float*)d_in[15];
    const float* b_b4   = (const float*)d_in[16];
    const float* w_cc   = (const float*)d_in[17];
    const float* b_cc   = (const float*)d_in[18];

    float* ws   = (float*)d_ws;
    float* out  = (float*)d_out;
    float* b123 = ws + WS_B123;
    float* b4   = ws + WS_B4;
    float* b2   = ws + WS_B2;
    float* b3   = ws + WS_B3;
    float* off2 = ws + WS_OFF2;
    float* off3 = ws + WS_OFF3;
    float* wp   = ws + WS_WPACK;
    float* bp   = ws + WS_BPACK;

    k_pack<<<dim3(768), dim3(256), 0, stream>>>(w_b1, w_b21, w_b31,
                                                b_b1, b_b21, b_b31, wp, bp);
    // b1 | b2i | b3i : one M=384 GEMM over x
    k_gemm1x1<<<dim3(32, 3, 8), dim3(256), 0, stream>>>(wp, bp, x, b123, 384);
    // b4 : maxpool(x) then 1x1 conv, pooling fused into staging
    k_gemm_b4<<<dim3(32, 1, 8), dim3(256), 0, stream>>>(w_b4, b_b4, x, b4);
    // offset convs
    k_conv_small<3, 18><<<dim3(4, 18, 8), dim3(256), 0, stream>>>(
        b123 + 128 * HW, (long)(384 * HW), w_off2, b_off2, off2);
    k_conv_small<5, 50><<<dim3(4, 50, 8), dim3(256), 0, stream>>>(
        b123 + 256 * HW, (long)(384 * HW), w_off3, b_off3, off3);
    // deformable convs
    k_deform<3><<<dim3(64, 1, 8), dim3(256), 0, stream>>>(
        b123 + 128 * HW, (long)(384 * HW), off2, w_ddc2, b_ddc2, b2);
    k_deform<5><<<dim3(64, 1, 8), dim3(256), 0, stream>>>(
        b123 + 256 * HW, (long)(384 * HW), off3, w_ddc3, b_ddc3, b3);
    // cat * x -> 1x1 conv 512->512 -> sigmoid -> + x
    k_gemm_final<<<dim3(32, 4, 8), dim3(256), 0, stream>>>(
        w_cc, b_cc, x, b123, b2, b3, b4, out);
}

// Round 2
// 1855.623 us; speedup vs baseline: 1.4676x; 1.4676x over previous
//
#include <hip/hip_runtime.h>
#include <math.h>

// Problem constants
#define HW 4096      // 64*64
#define NB 8         // batch

// ws layout in floats (~112.6 MB)
#define WS_B123  0ull          // [8][384][4096]  b1 | b2i->b2out | b3i->b3out
#define WS_B4    12582912ull   // [8][128][4096]
#define WS_T2    16777216ull   // [8][4096][128]  b2i NHWC
#define WS_T3    20971520ull   // [8][4096][128]  b3i NHWC
#define WS_OFF2  25165824ull   // [8][18][4096]
#define WS_OFF3  25755648ull   // [8][50][4096]
#define WS_WPACK 27394048ull   // [384][512]
#define WS_BPACK 27590656ull   // [384]
#define WS_WD2T  27591040ull   // [9][128][128]
#define WS_WD3T  27738496ull   // [25][128][128]

// ---------------------------------------------------------------- pack weights
__global__ void k_pack(const float* __restrict__ w1, const float* __restrict__ w21,
                       const float* __restrict__ w31, const float* __restrict__ b1,
                       const float* __restrict__ b21, const float* __restrict__ b31,
                       float* __restrict__ wp, float* __restrict__ bp) {
    int i = blockIdx.x * 256 + threadIdx.x;
    if (i < 384 * 512) {
        int o = i >> 9;
        float v;
        if (o < 128)      v = w1[i];
        else if (o < 256) v = w21[i - 128 * 512];
        else              v = w31[i - 256 * 512];
        wp[i] = v;
    }
    if (i < 384)
        bp[i] = (i < 128) ? b1[i] : (i < 256) ? b21[i - 128] : b31[i - 256];
}

// ------------------------------------------ transpose deform weights to [t][c][o]
__global__ void k_wtrans(const float* __restrict__ W, float* __restrict__ Wt, int TT) {
    int idx = blockIdx.x * 256 + threadIdx.x;
    if (idx < (size_t)16384 * TT) {
        int o = idx & 127;
        int c = (idx >> 7) & 127;
        int t = idx >> 14;
        Wt[idx] = W[(size_t)((o << 7) + c) * TT + t];
    }
}

// ---------------------------------------------- NCHW -> NHWC transpose (C=128)
__global__ __launch_bounds__(256) void k_tr(const float* __restrict__ src, long srcB,
                                            float* __restrict__ dst, long dstB) {
    __shared__ float t[32][33];
    const int p0 = blockIdx.x * 32, c0 = blockIdx.y * 32, b = blockIdx.z;
    const float* s = src + (size_t)b * srcB;
    float* d = dst + (size_t)b * dstB;
    #pragma unroll
    for (int ps = 0; ps < 4; ++ps) {
        int cl = ps * 8 + (threadIdx.x >> 5), pl = threadIdx.x & 31;
        t[cl][pl] = s[(size_t)(c0 + cl) * HW + p0 + pl];
    }
    __syncthreads();
    #pragma unroll
    for (int ps = 0; ps < 4; ++ps) {
        int pl = ps * 8 + (threadIdx.x >> 5), cl = threadIdx.x & 31;
        d[(size_t)(p0 + pl) * 128 + c0 + cl] = t[cl][pl];
    }
}

// ------------------------------------------------- 1x1 conv GEMM: out = W @ in
__global__ __launch_bounds__(256) void k_gemm1x1(
        const float* __restrict__ Wm, const float* __restrict__ bias,
        const float* __restrict__ In, float* __restrict__ Out, int M) {
    __shared__ float sA[16][128];
    __shared__ float sB[16][128];
    const int tid = threadIdx.x;
    const int p0 = blockIdx.x * 128;
    const int o0 = blockIdx.y * 128;
    const int b  = blockIdx.z;
    const float* inb = In + (size_t)b * 512 * HW;

    const int aO = tid & 127;
    const int aK = (tid >> 7) << 3;
    const int bK = tid >> 4;
    const int bP = (tid & 15) << 3;
    const int ot = (tid >> 4) << 3;
    const int pt = (tid & 15) << 3;

    float acc[8][8] = {};

    for (int k0 = 0; k0 < 512; k0 += 16) {
        const float* wrow = Wm + (size_t)(o0 + aO) * 512 + k0 + aK;
        float4 a0 = *(const float4*)(wrow);
        float4 a1 = *(const float4*)(wrow + 4);
        const float* src = inb + (size_t)(k0 + bK) * HW + p0 + bP;
        float4 b0 = *(const float4*)(src);
        float4 b1 = *(const float4*)(src + 4);
        __syncthreads();
        sA[aK + 0][aO] = a0.x; sA[aK + 1][aO] = a0.y;
        sA[aK + 2][aO] = a0.z; sA[aK + 3][aO] = a0.w;
        sA[aK + 4][aO] = a1.x; sA[aK + 5][aO] = a1.y;
        sA[aK + 6][aO] = a1.z; sA[aK + 7][aO] = a1.w;
        *(float4*)&sB[bK][bP]     = b0;
        *(float4*)&sB[bK][bP + 4] = b1;
        __syncthreads();
        #pragma unroll
        for (int kk = 0; kk < 16; ++kk) {
            float4 x0 = *(float4*)&sA[kk][ot];
            float4 x1 = *(float4*)&sA[kk][ot + 4];
            float4 y0 = *(float4*)&sB[kk][pt];
            float4 y1 = *(float4*)&sB[kk][pt + 4];
            float av[8] = {x0.x, x0.y, x0.z, x0.w, x1.x, x1.y, x1.z, x1.w};
            float bv[8] = {y0.x, y0.y, y0.z, y0.w, y1.x, y1.y, y1.z, y1.w};
            #pragma unroll
            for (int i = 0; i < 8; ++i)
                #pragma unroll
                for (int j = 0; j < 8; ++j)
                    acc[i][j] += av[i] * bv[j];
        }
    }
    #pragma unroll
    for (int i = 0; i < 8; ++i) {
        int o = o0 + ot + i;
        float bs = bias[o];
        float* dst = Out + ((size_t)b * M + o) * HW + p0 + pt;
        float4 r0 = {acc[i][0] + bs, acc[i][1] + bs, acc[i][2] + bs, acc[i][3] + bs};
        float4 r1 = {acc[i][4] + bs, acc[i][5] + bs, acc[i][6] + bs, acc[i][7] + bs};
        *(float4*)dst = r0;
        *(float4*)(dst + 4) = r1;
    }
}

// -------------------------------------- b4 GEMM with fused 3x3 maxpool staging
__global__ __launch_bounds__(256) void k_gemm_b4(
        const float* __restrict__ Wm, const float* __restrict__ bias,
        const float* __restrict__ X, float* __restrict__ Out) {
    __shared__ float sA[16][128];
    __shared__ float sB[16][128];
    __shared__ float tmp[16][4][64];
    const int tid = threadIdx.x;
    const int p0 = blockIdx.x * 128;
    const int h0 = blockIdx.x * 2;
    const int b  = blockIdx.z;
    const float* xb = X + (size_t)b * 512 * HW;

    const int aO = tid & 127;
    const int aK = (tid >> 7) << 3;
    const int bK = tid >> 4;
    const int bP = (tid & 15) << 3;
    const int ot = (tid >> 4) << 3;
    const int pt = (tid & 15) << 3;
    const int tC = tid >> 4;
    const int tBase = (tid & 15) << 4;

    float acc[8][8] = {};

    for (int k0 = 0; k0 < 512; k0 += 16) {
        const float* wrow = Wm + (size_t)aO * 512 + k0 + aK;
        float4 a0 = *(const float4*)(wrow);
        float4 a1 = *(const float4*)(wrow + 4);
        float4 t4[4];
        #pragma unroll
        for (int i = 0; i < 4; ++i) {
            int rw = tBase + i * 4;
            int r = rw >> 6, w = rw & 63;
            int hh = h0 - 1 + r;
            if (hh >= 0 && hh < 64)
                t4[i] = *(const float4*)(xb + (size_t)(k0 + tC) * HW + hh * 64 + w);
            else
                t4[i] = make_float4(-INFINITY, -INFINITY, -INFINITY, -INFINITY);
        }
        __syncthreads();
        sA[aK + 0][aO] = a0.x; sA[aK + 1][aO] = a0.y;
        sA[aK + 2][aO] = a0.z; sA[aK + 3][aO] = a0.w;
        sA[aK + 4][aO] = a1.x; sA[aK + 5][aO] = a1.y;
        sA[aK + 6][aO] = a1.z; sA[aK + 7][aO] = a1.w;
        #pragma unroll
        for (int i = 0; i < 4; ++i) {
            int rw = tBase + i * 4;
            *(float4*)&tmp[tC][rw >> 6][rw & 63] = t4[i];
        }
        __syncthreads();
        float sv[8];
        #pragma unroll
        for (int pp = 0; pp < 8; ++pp) {
            int pos = bP + pp;
            int lr = pos >> 6, w = pos & 63;
            float m = -INFINITY;
            #pragma unroll
            for (int rr = 0; rr < 3; ++rr) {
                m = fmaxf(m, tmp[bK][lr + rr][w]);
                if (w > 0)  m = fmaxf(m, tmp[bK][lr + rr][w - 1]);
                if (w < 63) m = fmaxf(m, tmp[bK][lr + rr][w + 1]);
            }
            sv[pp] = m;
        }
        *(float4*)&sB[bK][bP]     = make_float4(sv[0], sv[1], sv[2], sv[3]);
        *(float4*)&sB[bK][bP + 4] = make_float4(sv[4], sv[5], sv[6], sv[7]);
        __syncthreads();
        #pragma unroll
        for (int kk = 0; kk < 16; ++kk) {
            float4 x0 = *(float4*)&sA[kk][ot];
            float4 x1 = *(float4*)&sA[kk][ot + 4];
            float4 y0 = *(float4*)&sB[kk][pt];
            float4 y1 = *(float4*)&sB[kk][pt + 4];
            float av[8] = {x0.x, x0.y, x0.z, x0.w, x1.x, x1.y, x1.z, x1.w};
            float bv[8] = {y0.x, y0.y, y0.z, y0.w, y1.x, y1.y, y1.z, y1.w};
            #pragma unroll
            for (int i = 0; i < 8; ++i)
                #pragma unroll
                for (int j = 0; j < 8; ++j)
                    acc[i][j] += av[i] * bv[j];
        }
    }
    #pragma unroll
    for (int i = 0; i < 8; ++i) {
        int o = ot + i;
        float bs = bias[o];
        float* dst = Out + ((size_t)b * 128 + o) * HW + p0 + pt;
        float4 r0 = {acc[i][0] + bs, acc[i][1] + bs, acc[i][2] + bs, acc[i][3] + bs};
        float4 r1 = {acc[i][4] + bs, acc[i][5] + bs, acc[i][6] + bs, acc[i][7] + bs};
        *(float4*)dst = r0;
        *(float4*)(dst + 4) = r1;
    }
}

// ------------------------------------------- small direct conv (offset convs)
template<int KS, int OCH>
__global__ __launch_bounds__(256) void k_conv_small(
        const float* __restrict__ In, long inBStride,
        const float* __restrict__ Wt, const float* __restrict__ bias,
        float* __restrict__ Out) {
    constexpr int PAD = KS / 2;
    const int o = blockIdx.y;
    const int b = blockIdx.z;
    const int h = blockIdx.x * 16 + (threadIdx.x >> 4);
    const int w0 = (threadIdx.x & 15) << 2;
    const float* inb = In + (size_t)b * inBStride;
    const float* wo = Wt + (size_t)o * 128 * KS * KS;
    float bs = bias[o];
    float acc[4] = {bs, bs, bs, bs};
    for (int c = 0; c < 128; ++c) {
        const float* ip = inb + (size_t)c * HW;
        const float* wp = wo + c * KS * KS;
        float wreg[KS * KS];
        #pragma unroll
        for (int q = 0; q < KS * KS; ++q) wreg[q] = wp[q];
        #pragma unroll
        for (int ky = 0; ky < KS; ++ky) {
            int yy = h + ky - PAD;
            if (yy >= 0 && yy < 64) {
                const float* row = ip + yy * 64;
                float4 v0 = (w0 >= 4)  ? *(const float4*)(row + w0 - 4) : make_float4(0, 0, 0, 0);
                float4 v1 = *(const float4*)(row + w0);
                float4 v2 = (w0 <= 56) ? *(const float4*)(row + w0 + 4) : make_float4(0, 0, 0, 0);
                float wnd[12] = {v0.x, v0.y, v0.z, v0.w, v1.x, v1.y, v1.z, v1.w,
                                 v2.x, v2.y, v2.z, v2.w};
                #pragma unroll
                for (int kx = 0; kx < KS; ++kx) {
                    float wv = wreg[ky * KS + kx];
                    #pragma unroll
                    for (int i = 0; i < 4; ++i)
                        acc[i] += wnd[4 + i + kx - PAD] * wv;
                }
            }
        }
    }
    float* dst = Out + ((size_t)b * OCH + o) * HW + h * 64 + w0;
    *(float4*)dst = make_float4(acc[0], acc[1], acc[2], acc[3]);
}

// --------------------------------------------------------- deformable conv2d v2
// NHWC input, [t][c][o] weights. Block = (b, output row): 128 o x 64 pos.
template<int KS>
__global__ __launch_bounds__(256) void k_deform2(
        const float* __restrict__ Imn,   // [B][HW][128]
        const float* __restrict__ Off,   // [B][2*TT][HW]
        const float* __restrict__ Wt,    // [TT][128][128] (t,c,o)
        const float* __restrict__ bias,
        float* __restrict__ Out, long outBStride) {
    constexpr int PAD = KS / 2;
    constexpr int TT = KS * KS;
    __shared__ float sW[32][128];
    __shared__ float sS[32][68];
    __shared__ float4 wts4[64];
    __shared__ int2 c01[64];
    const int tid = threadIdx.x;
    const int hrow = blockIdx.x;
    const int b = blockIdx.z;
    const float* imn = Imn + (size_t)b * HW * 128;
    const float* offb = Off + (size_t)b * (2 * TT) * HW + hrow * 64;
    const int ot = (tid >> 4) << 3;   // 8 outputs
    const int pt = (tid & 15) << 2;   // 4 positions
    const int spos = tid & 63;        // sampling: my position
    const int scg = tid >> 6;         // sampling: 8-channel group within chunk
    float acc[8][4] = {};

    for (int t = 0; t < TT; ++t) {
        __syncthreads();
        if (tid < 64) {
            float dy = offb[(size_t)(2 * t) * HW + tid];
            float dx = offb[(size_t)(2 * t + 1) * HW + tid];
            float y = (float)(hrow + t / KS - PAD) + dy;
            float x = (float)(tid + t % KS - PAD) + dx;
            float y0f = floorf(y), x0f = floorf(x);
            float wy = y - y0f, wx = x - x0f;
            wts4[tid] = make_float4((1.f - wy) * (1.f - wx), (1.f - wy) * wx,
                                    wy * (1.f - wx), wy * wx);
            c01[tid] = make_int2((int)y0f, (int)x0f);
        }
        __syncthreads();
        for (int c0 = 0; c0 < 128; c0 += 32) {
            // stage weight fragment (coalesced)
            float4 wf[4];
            #pragma unroll
            for (int k = 0; k < 4; ++k) {
                int f = tid + k * 256;
                wf[k] = *(const float4*)&Wt[(size_t)(t * 128 + c0 + (f >> 5)) * 128 + ((f & 31) << 2)];
            }
            // bilinear sample 8 channels of my position (vectorized over C)
            float4 wq = wts4[spos];
            int2 cc = c01[spos];
            int y0 = cc.x, x0 = cc.y;
            bool yv0 = (unsigned)y0 < 64u, yv1 = (unsigned)(y0 + 1) < 64u;
            bool xv0 = (unsigned)x0 < 64u, xv1 = (unsigned)(x0 + 1) < 64u;
            const float* base = imn + ((size_t)(y0 * 64 + x0) * 128 + c0 + scg * 8);
            float a00[8] = {}, a01[8] = {}, a10[8] = {}, a11[8] = {};
            if (yv0 && xv0) { *(float4*)&a00[0] = *(const float4*)(base);
                              *(float4*)&a00[4] = *(const float4*)(base + 4); }
            if (yv0 && xv1) { *(float4*)&a01[0] = *(const float4*)(base + 128);
                              *(float4*)&a01[4] = *(const float4*)(base + 132); }
            if (yv1 && xv0) { *(float4*)&a10[0] = *(const float4*)(base + 64 * 128);
                              *(float4*)&a10[4] = *(const float4*)(base + 64 * 128 + 4); }
            if (yv1 && xv1) { *(float4*)&a11[0] = *(const float4*)(base + 65 * 128);
                              *(float4*)&a11[4] = *(const float4*)(base + 65 * 128 + 4); }
            float sv[8];
            #pragma unroll
            for (int i = 0; i < 8; ++i)
                sv[i] = wq.x * a00[i] + wq.y * a01[i] + wq.z * a10[i] + wq.w * a11[i];
            __syncthreads();   // previous chunk's GEMM done
            #pragma unroll
            for (int k = 0; k < 4; ++k) {
                int f = tid + k * 256;
                *(float4*)&sW[f >> 5][(f & 31) << 2] = wf[k];
            }
            #pragma unroll
            for (int i = 0; i < 8; ++i)
                sS[scg * 8 + i][spos] = sv[i];
            __syncthreads();
            #pragma unroll
            for (int kk = 0; kk < 32; ++kk) {
                float4 a0 = *(float4*)&sW[kk][ot];
                float4 a1 = *(float4*)&sW[kk][ot + 4];
                float4 bb = *(float4*)&sS[kk][pt];
                float av[8] = {a0.x, a0.y, a0.z, a0.w, a1.x, a1.y, a1.z, a1.w};
                float bv[4] = {bb.x, bb.y, bb.z, bb.w};
                #pragma unroll
                for (int i = 0; i < 8; ++i)
                    #pragma unroll
                    for (int j = 0; j < 4; ++j)
                        acc[i][j] += av[i] * bv[j];
            }
        }
    }
    #pragma unroll
    for (int i = 0; i < 8; ++i) {
        int o = ot + i;
        float bs = bias[o];
        float* dst = Out + (size_t)b * outBStride + (size_t)o * HW + hrow * 64 + pt;
        *(float4*)dst = make_float4(acc[i][0] + bs, acc[i][1] + bs,
                                    acc[i][2] + bs, acc[i][3] + bs);
    }
}

// -------------------------------------- final fuse: sigmoid(Wcc @ (cat*x)) + x
__global__ __launch_bounds__(256) void k_gemm_final(
        const float* __restrict__ Wm, const float* __restrict__ bias,
        const float* __restrict__ X,
        const float* __restrict__ B123, const float* __restrict__ B4,
        float* __restrict__ OutF) {
    __shared__ float sA[16][128];
    __shared__ float sB[16][128];
    const int tid = threadIdx.x;
    const int p0 = blockIdx.x * 128;
    const int o0 = blockIdx.y * 128;
    const int b  = blockIdx.z;
    const int aO = tid & 127;
    const int aK = (tid >> 7) << 3;
    const int bK = tid >> 4;
    const int bP = (tid & 15) << 3;
    const int ot = (tid >> 4) << 3;
    const int pt = (tid & 15) << 3;
    float acc[8][8] = {};

    for (int k0 = 0; k0 < 512; k0 += 16) {
        const float* wrow = Wm + (size_t)(o0 + aO) * 512 + k0 + aK;
        float4 a0 = *(const float4*)(wrow);
        float4 a1 = *(const float4*)(wrow + 4);
        int c = k0 + bK;
        const float* br = (c < 384) ? B123 + ((size_t)b * 384 + c) * HW
                                    : B4 + ((size_t)b * 128 + (c - 384)) * HW;
        const float* xr = X + ((size_t)b * 512 + c) * HW + p0 + bP;
        float4 u0 = *(const float4*)(br + p0 + bP);
        float4 u1 = *(const float4*)(br + p0 + bP + 4);
        float4 z0 = *(const float4*)(xr);
        float4 z1 = *(const float4*)(xr + 4);
        float4 m0 = {u0.x * z0.x, u0.y * z0.y, u0.z * z0.z, u0.w * z0.w};
        float4 m1 = {u1.x * z1.x, u1.y * z1.y, u1.z * z1.z, u1.w * z1.w};
        __syncthreads();
        sA[aK + 0][aO] = a0.x; sA[aK + 1][aO] = a0.y;
        sA[aK + 2][aO] = a0.z; sA[aK + 3][aO] = a0.w;
        sA[aK + 4][aO] = a1.x; sA[aK + 5][aO] = a1.y;
        sA[aK + 6][aO] = a1.z; sA[aK + 7][aO] = a1.w;
        *(float4*)&sB[bK][bP]     = m0;
        *(float4*)&sB[bK][bP + 4] = m1;
        __syncthreads();
        #pragma unroll
        for (int kk = 0; kk < 16; ++kk) {
            float4 x0 = *(float4*)&sA[kk][ot];
            float4 x1 = *(float4*)&sA[kk][ot + 4];
            float4 y0 = *(float4*)&sB[kk][pt];
            float4 y1 = *(float4*)&sB[kk][pt + 4];
            float av[8] = {x0.x, x0.y, x0.z, x0.w, x1.x, x1.y, x1.z, x1.w};
            float bv[8] = {y0.x, y0.y, y0.z, y0.w, y1.x, y1.y, y1.z, y1.w};
            #pragma unroll
            for (int i = 0; i < 8; ++i)
                #pragma unroll
                for (int j = 0; j < 8; ++j)
                    acc[i][j] += av[i] * bv[j];
        }
    }
    #pragma unroll
    for (int i = 0; i < 8; ++i) {
        int o = o0 + ot + i;
        float bs = bias[o];
        const float* xo = X + ((size_t)b * 512 + o) * HW + p0 + pt;
        float4 xv0 = *(const float4*)(xo);
        float4 xv1 = *(const float4*)(xo + 4);
        float r[8];
        #pragma unroll
        for (int j = 0; j < 8; ++j) {
            float f = acc[i][j] + bs;
            float sg = 1.f / (1.f + __expf(-f));
            float xv = (j < 4) ? ((const float*)&xv0)[j] : ((const float*)&xv1)[j - 4];
            r[j] = xv + sg;
        }
        float* dst = OutF + ((size_t)b * 512 + o) * HW + p0 + pt;
        *(float4*)dst = make_float4(r[0], r[1], r[2], r[3]);
        *(float4*)(dst + 4) = make_float4(r[4], r[5], r[6], r[7]);
    }
}

// ------------------------------------------------------------------- launcher
extern "C" void kernel_launch(void* const* d_in, const int* in_sizes, int n_in,
                              void* d_out, int out_size, void* d_ws, size_t ws_size,
                              hipStream_t stream) {
    const float* x      = (const float*)d_in[0];
    const float* w_b1   = (const float*)d_in[1];
    const float* b_b1   = (const float*)d_in[2];
    const float* w_b21  = (const float*)d_in[3];
    const float* b_b21  = (const float*)d_in[4];
    const float* w_off2 = (const float*)d_in[5];
    const float* b_off2 = (const float*)d_in[6];
    const float* w_ddc2 = (const float*)d_in[7];
    const float* b_ddc2 = (const float*)d_in[8];
    const float* w_b31  = (const float*)d_in[9];
    const float* b_b31  = (const float*)d_in[10];
    const float* w_off3 = (const float*)d_in[11];
    const float* b_off3 = (const float*)d_in[12];
    const float* w_ddc3 = (const float*)d_in[13];
    const float* b_ddc3 = (const float*)d_in[14];
    const float* w_b4   = (const float*)d_in[15];
    const float* b_b4   = (const float*)d_in[16];
    const float* w_cc   = (const float*)d_in[17];
    const float* b_cc   = (const float*)d_in[18];

    float* ws   = (float*)d_ws;
    float* out  = (float*)d_out;
    float* b123 = ws + WS_B123;
    float* b4   = ws + WS_B4;
    float* t2   = ws + WS_T2;
    float* t3   = ws + WS_T3;
    float* off2 = ws + WS_OFF2;
    float* off3 = ws + WS_OFF3;
    float* wp   = ws + WS_WPACK;
    float* bp   = ws + WS_BPACK;
    float* wd2t = ws + WS_WD2T;
    float* wd3t = ws + WS_WD3T;

    k_pack<<<dim3(768), dim3(256), 0, stream>>>(w_b1, w_b21, w_b31,
                                                b_b1, b_b21, b_b31, wp, bp);
    k_wtrans<<<dim3(576), dim3(256), 0, stream>>>(w_ddc2, wd2t, 9);
    k_wtrans<<<dim3(1600), dim3(256), 0, stream>>>(w_ddc3, wd3t, 25);
    // b1 | b2i | b3i : one M=384 GEMM over x (NCHW)
    k_gemm1x1<<<dim3(32, 3, 8), dim3(256), 0, stream>>>(wp, bp, x, b123, 384);
    // b4 : maxpool(x) then 1x1 conv, pooling fused into staging
    k_gemm_b4<<<dim3(32, 1, 8), dim3(256), 0, stream>>>(w_b4, b_b4, x, b4);
    // offset convs (read NCHW b2i/b3i)
    k_conv_small<3, 18><<<dim3(4, 18, 8), dim3(256), 0, stream>>>(
        b123 + 128 * HW, (long)(384 * HW), w_off2, b_off2, off2);
    k_conv_small<5, 50><<<dim3(4, 50, 8), dim3(256), 0, stream>>>(
        b123 + 256 * HW, (long)(384 * HW), w_off3, b_off3, off3);
    // NHWC copies for deform sampling
    k_tr<<<dim3(128, 4, 8), dim3(256), 0, stream>>>(
        b123 + 128 * HW, (long)(384 * HW), t2, (long)(HW * 128));
    k_tr<<<dim3(128, 4, 8), dim3(256), 0, stream>>>(
        b123 + 256 * HW, (long)(384 * HW), t3, (long)(HW * 128));
    // deformable convs -> overwrite dead b2i/b3i slices of B123
    k_deform2<3><<<dim3(64, 1, 8), dim3(256), 0, stream>>>(
        t2, off2, wd2t, b_ddc2, b123 + 128 * HW, (long)(384 * HW));
    k_deform2<5><<<dim3(64, 1, 8), dim3(256), 0, stream>>>(
        t3, off3, wd3t, b_ddc3, b123 + 256 * HW, (long)(384 * HW));
    // cat * x -> 1x1 conv 512->512 -> sigmoid -> + x
    k_gemm_final<<<dim3(32, 4, 8), dim3(256), 0, stream>>>(
        w_cc, b_cc, x, b123, b4, out);
}

// Round 3
// 748.410 us; speedup vs baseline: 3.6388x; 2.4794x over previous
//
#include <hip/hip_runtime.h>
#include <math.h>

#define HW 4096
typedef short short8 __attribute__((ext_vector_type(8)));
typedef float floatx4 __attribute__((ext_vector_type(4)));

// ---- ws layout (bytes) ----
#define O_XBT   0ull            // [8][4096][512] bf16 x NHWC
#define O_PXB   33554432ull     // [8][4096][512] bf16 pooled x NHWC (reused later)
#define O_CATB  67108864ull     // [8][4096][512] bf16 cat branches NHWC
#define O_WPB   100663296ull    // [384][512] bf16
#define O_W4B   101056512ull    // [128][512] bf16
#define O_WCCB  101187584ull    // [512][512] bf16
#define O_WD2T  101711872ull    // [9][128][128] bf16
#define O_WD3T  102006784ull    // [25][128][128] bf16
#define O_WO2T  102825984ull    // [9][64][128] bf16
#define O_WO3T  102973440ull    // [25][64][128] bf16
// reuse of PXB region after b4 GEMM:
#define O_T2B   33554432ull     // [8][4096][128] bf16 b2i NHWC
#define O_T3B   41943040ull     // [8][4096][128] bf16 b3i NHWC
#define O_OFF2  50331648ull     // [8][18][4096] f32
#define O_OFF3  52690944ull     // [8][50][4096] f32

__device__ __forceinline__ unsigned short f2b(float f) {
    union { float f; unsigned u; } v; v.f = f;
    unsigned r = v.u + 0x7FFFu + ((v.u >> 16) & 1u);
    return (unsigned short)(r >> 16);
}
__device__ __forceinline__ float b2f(unsigned short s) {
    union { unsigned u; float f; } v; v.u = ((unsigned)s) << 16; return v.f;
}
__device__ __forceinline__ float lou(unsigned u) {
    union { unsigned u; float f; } v; v.u = u << 16; return v.f;
}
__device__ __forceinline__ float hiu(unsigned u) {
    union { unsigned u; float f; } v; v.u = u & 0xFFFF0000u; return v.f;
}
__device__ __forceinline__ unsigned pk2(float lo, float hi) {
    return (unsigned)f2b(lo) | ((unsigned)f2b(hi) << 16);
}

// ------------------------------------------------------------- weight prep
__global__ __launch_bounds__(256) void k_prepw(
        const float* __restrict__ w1, const float* __restrict__ w21,
        const float* __restrict__ w31, const float* __restrict__ w4,
        const float* __restrict__ wcc, const float* __restrict__ wd2,
        const float* __restrict__ wd3, const float* __restrict__ wo2,
        const float* __restrict__ wo3, unsigned short* __restrict__ ws8) {
    unsigned i = blockIdx.x * 256 + threadIdx.x;
    unsigned short* wpb  = ws8 + (O_WPB  >> 1);
    unsigned short* w4b  = ws8 + (O_W4B  >> 1);
    unsigned short* wccb = ws8 + (O_WCCB >> 1);
    unsigned short* wd2t = ws8 + (O_WD2T >> 1);
    unsigned short* wd3t = ws8 + (O_WD3T >> 1);
    unsigned short* wo2t = ws8 + (O_WO2T >> 1);
    unsigned short* wo3t = ws8 + (O_WO3T >> 1);
    if (i < 196608) {
        int o = i >> 9;
        float v = (o < 128) ? w1[i] : (o < 256) ? w21[i - 65536] : w31[i - 131072];
        wpb[i] = f2b(v);
    } else if (i < 262144) {
        unsigned j = i - 196608; w4b[j] = f2b(w4[j]);
    } else if (i < 524288) {
        unsigned j = i - 262144; wccb[j] = f2b(wcc[j]);
    } else if (i < 671744) {
        unsigned j = i - 524288; int t = j >> 14, o = (j >> 7) & 127, c = j & 127;
        wd2t[j] = f2b(wd2[((o * 128 + c) * 9) + t]);
    } else if (i < 1081344) {
        unsigned j = i - 671744; int t = j >> 14, o = (j >> 7) & 127, c = j & 127;
        wd3t[j] = f2b(wd3[((o * 128 + c) * 25) + t]);
    } else if (i < 1155072) {
        unsigned j = i - 1081344; int t = j >> 13, o = (j >> 7) & 63, c = j & 127;
        wo2t[j] = (o < 18) ? f2b(wo2[((o * 128 + c) * 9) + t]) : 0;
    } else if (i < 1359872) {
        unsigned j = i - 1155072; int t = j >> 13, o = (j >> 7) & 63, c = j & 127;
        wo3t[j] = (o < 50) ? f2b(wo3[((o * 128 + c) * 25) + t]) : 0;
    }
}

// ---------------------------------------- x NCHW f32 -> NHWC bf16 transpose
__global__ __launch_bounds__(256) void k_xpose(const float* __restrict__ X,
                                               unsigned short* __restrict__ xbT) {
    __shared__ unsigned short t[32][33];
    const int p0 = blockIdx.x * 32, c0 = blockIdx.y * 32, b = blockIdx.z;
    const int tid = threadIdx.x;
    #pragma unroll
    for (int s = 0; s < 4; ++s) {
        int cl = s * 8 + (tid >> 5), pl = tid & 31;
        t[cl][pl] = f2b(X[((size_t)b * 512 + c0 + cl) * HW + p0 + pl]);
    }
    __syncthreads();
    #pragma unroll
    for (int s = 0; s < 4; ++s) {
        int pl = s * 8 + (tid >> 5), cl = tid & 31;
        xbT[((size_t)b * HW + p0 + pl) * 512 + c0 + cl] = t[cl][pl];
    }
}

// ----------------------------------------------- 3x3 s1 maxpool on NHWC bf16
__global__ __launch_bounds__(256) void k_pool(const unsigned short* __restrict__ xbT,
                                              unsigned short* __restrict__ pxb) {
    unsigned gid = blockIdx.x * 256 + threadIdx.x;   // 8*4096*64
    int b = gid >> 18;
    unsigned rem = gid & 262143;
    int pos = rem >> 6;
    int cg = (rem & 63) * 8;
    int h = pos >> 6, w = pos & 63;
    const unsigned short* img = xbT + (size_t)b * HW * 512;
    float m[8] = {-INFINITY, -INFINITY, -INFINITY, -INFINITY,
                  -INFINITY, -INFINITY, -INFINITY, -INFINITY};
    #pragma unroll
    for (int dy = -1; dy <= 1; ++dy) {
        int hh = h + dy;
        if (hh < 0 || hh >= 64) continue;
        #pragma unroll
        for (int dx = -1; dx <= 1; ++dx) {
            int ww = w + dx;
            if (ww < 0 || ww >= 64) continue;
            uint4 v = *(const uint4*)(img + ((size_t)(hh * 64 + ww)) * 512 + cg);
            unsigned uu[4] = {v.x, v.y, v.z, v.w};
            #pragma unroll
            for (int e = 0; e < 4; ++e) {
                m[2 * e]     = fmaxf(m[2 * e],     lou(uu[e]));
                m[2 * e + 1] = fmaxf(m[2 * e + 1], hiu(uu[e]));
            }
        }
    }
    uint4 o;
    o.x = pk2(m[0], m[1]); o.y = pk2(m[2], m[3]);
    o.z = pk2(m[4], m[5]); o.w = pk2(m[6], m[7]);
    *(uint4*)(pxb + ((size_t)b * HW + pos) * 512 + cg) = o;
}

// ----------------------------- bf16 MFMA GEMM: C[128 x 128pos] = A[128x512]B
// A row-major bf16 lda=512; B = NHWC bf16 [B][4096][512]; out NHWC bf16.
__global__ __launch_bounds__(256) void k_gemm(
        const unsigned short* __restrict__ A, const float* __restrict__ bias,
        const unsigned short* __restrict__ Bm,
        unsigned short* __restrict__ dst, int dStride, int dOff) {
    __shared__ unsigned short sA[128][40];
    __shared__ unsigned short sB[128][40];
    const int tid = threadIdx.x;
    const int n0 = blockIdx.x * 128;
    const int b = blockIdx.z;
    const int wave = tid >> 6, lane = tid & 63, quad = lane >> 4, lr = lane & 15;
    const int m0w = (wave & 1) * 64, n0w = (wave >> 1) * 64;
    const int srow = tid >> 1, skh = (tid & 1) * 16;
    floatx4 acc[4][4] = {};

    for (int k0 = 0; k0 < 512; k0 += 32) {
        const unsigned short* ga = A + (size_t)srow * 512 + k0 + skh;
        uint4 a0 = *(const uint4*)(ga);
        uint4 a1 = *(const uint4*)(ga + 8);
        const unsigned short* gb = Bm + ((size_t)b * HW + n0 + srow) * 512 + k0 + skh;
        uint4 b0 = *(const uint4*)(gb);
        uint4 b1 = *(const uint4*)(gb + 8);
        __syncthreads();
        *(uint4*)&sA[srow][skh] = a0;
        *(uint4*)&sA[srow][skh + 8] = a1;
        *(uint4*)&sB[srow][skh] = b0;
        *(uint4*)&sB[srow][skh + 8] = b1;
        __syncthreads();
        short8 af[4], bf[4];
        #pragma unroll
        for (int i = 0; i < 4; ++i) af[i] = *(short8*)&sA[m0w + i * 16 + lr][quad * 8];
        #pragma unroll
        for (int j = 0; j < 4; ++j) bf[j] = *(short8*)&sB[n0w + j * 16 + lr][quad * 8];
        #pragma unroll
        for (int i = 0; i < 4; ++i)
            #pragma unroll
            for (int j = 0; j < 4; ++j)
                acc[i][j] = __builtin_amdgcn_mfma_f32_16x16x32_bf16(af[i], bf[j], acc[i][j], 0, 0, 0);
    }
    #pragma unroll
    for (int i = 0; i < 4; ++i) {
        float4 bs = *(const float4*)&bias[m0w + i * 16 + quad * 4];
        #pragma unroll
        for (int j = 0; j < 4; ++j) {
            floatx4 v = acc[i][j];
            unsigned u0 = pk2(v[0] + bs.x, v[1] + bs.y);
            unsigned u1 = pk2(v[2] + bs.z, v[3] + bs.w);
            int pos = n0 + n0w + j * 16 + lr;
            int mm = m0w + i * 16 + quad * 4;
            uint2 st; st.x = u0; st.y = u1;
            *(uint2*)&dst[((size_t)b * HW + pos) * dStride + dOff + mm] = st;
        }
    }
}

// ------------------------------------ offset convs via MFMA (M=64 padded)
template<int KS, int OCH>
__global__ __launch_bounds__(256) void k_offconv(
        const unsigned short* __restrict__ img,   // [B][4096][128] bf16
        const unsigned short* __restrict__ woT,   // [TT][64][128] bf16
        const float* __restrict__ bias, float* __restrict__ Out) {
    constexpr int PAD = KS / 2;
    constexpr int TT = KS * KS;
    __shared__ unsigned short sW[64][136];
    __shared__ unsigned short sS[64][136];
    const int tid = threadIdx.x;
    const int hrow = blockIdx.x, b = blockIdx.z;
    const int wave = tid >> 6, lane = tid & 63, quad = lane >> 4, lr = lane & 15;
    const int m0w = (wave & 1) * 32, n0w = (wave >> 1) * 32;
    const int row = tid >> 2, q4 = (tid & 3) * 32;
    const unsigned short* ib = img + (size_t)b * HW * 128;
    floatx4 acc[2][2] = {};

    for (int t = 0; t < TT; ++t) {
        int ky = t / KS, kx = t % KS;
        int r = hrow + ky - PAD;
        const uint4* wsrc = (const uint4*)(woT + ((size_t)t * 64 + row) * 128 + q4);
        uint4 wv[4] = {wsrc[0], wsrc[1], wsrc[2], wsrc[3]};
        int xcol = row + kx - PAD;   // row == pos here
        uint4 sv[4] = {};
        if ((unsigned)r < 64u && (unsigned)xcol < 64u) {
            const uint4* ssrc = (const uint4*)(ib + ((size_t)(r * 64 + xcol)) * 128 + q4);
            sv[0] = ssrc[0]; sv[1] = ssrc[1]; sv[2] = ssrc[2]; sv[3] = ssrc[3];
        }
        __syncthreads();
        #pragma unroll
        for (int j = 0; j < 4; ++j) {
            *(uint4*)&sW[row][q4 + j * 8] = wv[j];
            *(uint4*)&sS[row][q4 + j * 8] = sv[j];
        }
        __syncthreads();
        #pragma unroll
        for (int ks = 0; ks < 4; ++ks) {
            short8 af[2], bf[2];
            #pragma unroll
            for (int i = 0; i < 2; ++i)
                af[i] = *(short8*)&sW[m0w + i * 16 + lr][ks * 32 + quad * 8];
            #pragma unroll
            for (int j = 0; j < 2; ++j)
                bf[j] = *(short8*)&sS[n0w + j * 16 + lr][ks * 32 + quad * 8];
            #pragma unroll
            for (int i = 0; i < 2; ++i)
                #pragma unroll
                for (int j = 0; j < 2; ++j)
                    acc[i][j] = __builtin_amdgcn_mfma_f32_16x16x32_bf16(af[i], bf[j], acc[i][j], 0, 0, 0);
        }
    }
    #pragma unroll
    for (int i = 0; i < 2; ++i) {
        #pragma unroll
        for (int j = 0; j < 2; ++j) {
            floatx4 v = acc[i][j];
            int col = n0w + j * 16 + lr;
            #pragma unroll
            for (int rg = 0; rg < 4; ++rg) {
                int o = m0w + i * 16 + quad * 4 + rg;
                if (o < OCH)
                    Out[((size_t)b * OCH + o) * HW + hrow * 64 + col] = v[rg] + bias[o];
            }
        }
    }
}

// ----------------------------------------------- deformable conv via MFMA
template<int KS>
__global__ __launch_bounds__(256) void k_deform3(
        const unsigned short* __restrict__ img,   // [B][4096][128] bf16
        const float* __restrict__ Off,            // [B][2TT][4096] f32
        const unsigned short* __restrict__ wdT,   // [TT][128][128] bf16
        const float* __restrict__ bias,
        unsigned short* __restrict__ catb, int dOff) {
    constexpr int PAD = KS / 2;
    constexpr int TT = KS * KS;
    __shared__ unsigned short sW[128][136];
    __shared__ unsigned short sS[64][136];
    const int tid = threadIdx.x;
    const int hrow = blockIdx.x, b = blockIdx.z;
    const int wave = tid >> 6, lane = tid & 63, quad = lane >> 4, lr = lane & 15;
    const int m0w = (wave & 1) * 64, n0w = (wave >> 1) * 32;
    const int pos = tid >> 2, cq = (tid & 3) * 32;
    const int wrow = tid >> 1, whalf = (tid & 1) * 64;
    const unsigned short* ib = img + (size_t)b * HW * 128;
    const float* offb = Off + (size_t)b * 2 * TT * HW + hrow * 64;
    floatx4 acc[4][2] = {};

    for (int t = 0; t < TT; ++t) {
        // per-thread offsets for my pos
        float dy = offb[(size_t)(2 * t) * HW + pos];
        float dx = offb[(size_t)(2 * t + 1) * HW + pos];
        float fy = (float)(hrow + t / KS - PAD) + dy;
        float fx = (float)(pos + t % KS - PAD) + dx;
        float y0f = floorf(fy), x0f = floorf(fx);
        float wy = fy - y0f, wx = fx - x0f;
        int y0 = (int)y0f, x0 = (int)x0f;
        float w00 = (1.f - wy) * (1.f - wx), w01 = (1.f - wy) * wx;
        float w10 = wy * (1.f - wx), w11 = wy * wx;
        // weight tile global loads
        const uint4* wsrc = (const uint4*)(wdT + ((size_t)t * 128 + wrow) * 128 + whalf);
        uint4 wv[8];
        #pragma unroll
        for (int j = 0; j < 8; ++j) wv[j] = wsrc[j];
        // corner loads (32 channels = 4 x uint4 per corner)
        bool yv0 = (unsigned)y0 < 64u, yv1 = (unsigned)(y0 + 1) < 64u;
        bool xv0 = (unsigned)x0 < 64u, xv1 = (unsigned)(x0 + 1) < 64u;
        uint4 cA[4] = {}, cB[4] = {}, cC[4] = {}, cD[4] = {};
        const unsigned short* base = ib + ((size_t)(y0 * 64 + x0)) * 128 + cq;
        if (yv0 && xv0) { const uint4* p = (const uint4*)(base);
            cA[0]=p[0]; cA[1]=p[1]; cA[2]=p[2]; cA[3]=p[3]; }
        if (yv0 && xv1) { const uint4* p = (const uint4*)(base + 128);
            cB[0]=p[0]; cB[1]=p[1]; cB[2]=p[2]; cB[3]=p[3]; }
        if (yv1 && xv0) { const uint4* p = (const uint4*)(base + 64 * 128);
            cC[0]=p[0]; cC[1]=p[1]; cC[2]=p[2]; cC[3]=p[3]; }
        if (yv1 && xv1) { const uint4* p = (const uint4*)(base + 65 * 128);
            cD[0]=p[0]; cD[1]=p[1]; cD[2]=p[2]; cD[3]=p[3]; }
        uint4 outv[4];
        #pragma unroll
        for (int j = 0; j < 4; ++j) {
            unsigned a[4] = {cA[j].x, cA[j].y, cA[j].z, cA[j].w};
            unsigned bb[4] = {cB[j].x, cB[j].y, cB[j].z, cB[j].w};
            unsigned c[4] = {cC[j].x, cC[j].y, cC[j].z, cC[j].w};
            unsigned d[4] = {cD[j].x, cD[j].y, cD[j].z, cD[j].w};
            unsigned r[4];
            #pragma unroll
            for (int e = 0; e < 4; ++e) {
                float lo = w00 * lou(a[e]) + w01 * lou(bb[e]) + w10 * lou(c[e]) + w11 * lou(d[e]);
                float hi = w00 * hiu(a[e]) + w01 * hiu(bb[e]) + w10 * hiu(c[e]) + w11 * hiu(d[e]);
                r[e] = pk2(lo, hi);
            }
            outv[j].x = r[0]; outv[j].y = r[1]; outv[j].z = r[2]; outv[j].w = r[3];
        }
        __syncthreads();
        #pragma unroll
        for (int j = 0; j < 8; ++j)
            *(uint4*)&sW[wrow][whalf + j * 8] = wv[j];
        #pragma unroll
        for (int j = 0; j < 4; ++j)
            *(uint4*)&sS[pos][cq + j * 8] = outv[j];
        __syncthreads();
        #pragma unroll
        for (int ks = 0; ks < 4; ++ks) {
            short8 af[4], bf[2];
            #pragma unroll
            for (int i = 0; i < 4; ++i)
                af[i] = *(short8*)&sW[m0w + i * 16 + lr][ks * 32 + quad * 8];
            #pragma unroll
            for (int j = 0; j < 2; ++j)
                bf[j] = *(short8*)&sS[n0w + j * 16 + lr][ks * 32 + quad * 8];
            #pragma unroll
            for (int i = 0; i < 4; ++i)
                #pragma unroll
                for (int j = 0; j < 2; ++j)
                    acc[i][j] = __builtin_amdgcn_mfma_f32_16x16x32_bf16(af[i], bf[j], acc[i][j], 0, 0, 0);
        }
    }
    #pragma unroll
    for (int i = 0; i < 4; ++i) {
        float4 bs = *(const float4*)&bias[m0w + i * 16 + quad * 4];
        #pragma unroll
        for (int j = 0; j < 2; ++j) {
            floatx4 v = acc[i][j];
            unsigned u0 = pk2(v[0] + bs.x, v[1] + bs.y);
            unsigned u1 = pk2(v[2] + bs.z, v[3] + bs.w);
            int col = n0w + j * 16 + lr;
            int mm = m0w + i * 16 + quad * 4;
            uint2 st; st.x = u0; st.y = u1;
            *(uint2*)&catb[((size_t)b * HW + hrow * 64 + col) * 512 + dOff + mm] = st;
        }
    }
}

// ------------------- final: sigmoid(Wcc @ (catb*xbT)) + x, fp32 NCHW output
__global__ __launch_bounds__(256) void k_gemm_final(
        const unsigned short* __restrict__ A, const float* __restrict__ bias,
        const unsigned short* __restrict__ catb, const unsigned short* __restrict__ xbT,
        const float* __restrict__ X, float* __restrict__ OutF) {
    __shared__ unsigned short sA[128][40];
    __shared__ unsigned short sB[128][40];
    const int tid = threadIdx.x;
    const int n0 = blockIdx.x * 128;
    const int o0 = blockIdx.y * 128;
    const int b = blockIdx.z;
    const int wave = tid >> 6, lane = tid & 63, quad = lane >> 4, lr = lane & 15;
    const int m0w = (wave & 1) * 64, n0w = (wave >> 1) * 64;
    const int srow = tid >> 1, skh = (tid & 1) * 16;
    floatx4 acc[4][4] = {};

    for (int k0 = 0; k0 < 512; k0 += 32) {
        const unsigned short* ga = A + (size_t)(o0 + srow) * 512 + k0 + skh;
        uint4 a0 = *(const uint4*)(ga);
        uint4 a1 = *(const uint4*)(ga + 8);
        size_t bi = ((size_t)b * HW + n0 + srow) * 512 + k0 + skh;
        uint4 c0 = *(const uint4*)(catb + bi);
        uint4 c1 = *(const uint4*)(catb + bi + 8);
        uint4 x0 = *(const uint4*)(xbT + bi);
        uint4 x1 = *(const uint4*)(xbT + bi + 8);
        unsigned cu[8] = {c0.x, c0.y, c0.z, c0.w, c1.x, c1.y, c1.z, c1.w};
        unsigned xu[8] = {x0.x, x0.y, x0.z, x0.w, x1.x, x1.y, x1.z, x1.w};
        unsigned mu[8];
        #pragma unroll
        for (int e = 0; e < 8; ++e)
            mu[e] = pk2(lou(cu[e]) * lou(xu[e]), hiu(cu[e]) * hiu(xu[e]));
        __syncthreads();
        *(uint4*)&sA[srow][skh] = a0;
        *(uint4*)&sA[srow][skh + 8] = a1;
        uint4 m0v; m0v.x = mu[0]; m0v.y = mu[1]; m0v.z = mu[2]; m0v.w = mu[3];
        uint4 m1v; m1v.x = mu[4]; m1v.y = mu[5]; m1v.z = mu[6]; m1v.w = mu[7];
        *(uint4*)&sB[srow][skh] = m0v;
        *(uint4*)&sB[srow][skh + 8] = m1v;
        __syncthreads();
        short8 af[4], bf[4];
        #pragma unroll
        for (int i = 0; i < 4; ++i) af[i] = *(short8*)&sA[m0w + i * 16 + lr][quad * 8];
        #pragma unroll
        for (int j = 0; j < 4; ++j) bf[j] = *(short8*)&sB[n0w + j * 16 + lr][quad * 8];
        #pragma unroll
        for (int i = 0; i < 4; ++i)
            #pragma unroll
            for (int j = 0; j < 4; ++j)
                acc[i][j] = __builtin_amdgcn_mfma_f32_16x16x32_bf16(af[i], bf[j], acc[i][j], 0, 0, 0);
    }
    #pragma unroll
    for (int i = 0; i < 4; ++i) {
        float4 bs = *(const float4*)&bias[o0 + m0w + i * 16 + quad * 4];
        float bsa[4] = {bs.x, bs.y, bs.z, bs.w};
        #pragma unroll
        for (int j = 0; j < 4; ++j) {
            floatx4 v = acc[i][j];
            int pos = n0 + n0w + j * 16 + lr;
            #pragma unroll
            for (int rg = 0; rg < 4; ++rg) {
                int o = o0 + m0w + i * 16 + quad * 4 + rg;
                float f = v[rg] + bsa[rg];
                float sg = 1.f / (1.f + __expf(-f));
                size_t idx = ((size_t)b * 512 + o) * HW + pos;
                OutF[idx] = X[idx] + sg;
            }
        }
    }
}

// ------------------------------------------------------------------- launcher
extern "C" void kernel_launch(void* const* d_in, const int* in_sizes, int n_in,
                              void* d_out, int out_size, void* d_ws, size_t ws_size,
                              hipStream_t stream) {
    const float* x      = (const float*)d_in[0];
    const float* w_b1   = (const float*)d_in[1];
    const float* b_b1   = (const float*)d_in[2];
    const float* w_b21  = (const float*)d_in[3];
    const float* b_b21  = (const float*)d_in[4];
    const float* w_off2 = (const float*)d_in[5];
    const float* b_off2 = (const float*)d_in[6];
    const float* w_ddc2 = (const float*)d_in[7];
    const float* b_ddc2 = (const float*)d_in[8];
    const float* w_b31  = (const float*)d_in[9];
    const float* b_b31  = (const float*)d_in[10];
    const float* w_off3 = (const float*)d_in[11];
    const float* b_off3 = (const float*)d_in[12];
    const float* w_ddc3 = (const float*)d_in[13];
    const float* b_ddc3 = (const float*)d_in[14];
    const float* w_b4   = (const float*)d_in[15];
    const float* b_b4   = (const float*)d_in[16];
    const float* w_cc   = (const float*)d_in[17];
    const float* b_cc   = (const float*)d_in[18];

    char* wsb = (char*)d_ws;
    unsigned short* ws8  = (unsigned short*)d_ws;
    unsigned short* xbT  = (unsigned short*)(wsb + O_XBT);
    unsigned short* pxb  = (unsigned short*)(wsb + O_PXB);
    unsigned short* catb = (unsigned short*)(wsb + O_CATB);
    unsigned short* wpb  = (unsigned short*)(wsb + O_WPB);
    unsigned short* w4b  = (unsigned short*)(wsb + O_W4B);
    unsigned short* wccb = (unsigned short*)(wsb + O_WCCB);
    unsigned short* wd2t = (unsigned short*)(wsb + O_WD2T);
    unsigned short* wd3t = (unsigned short*)(wsb + O_WD3T);
    unsigned short* wo2t = (unsigned short*)(wsb + O_WO2T);
    unsigned short* wo3t = (unsigned short*)(wsb + O_WO3T);
    unsigned short* t2b  = (unsigned short*)(wsb + O_T2B);
    unsigned short* t3b  = (unsigned short*)(wsb + O_T3B);
    float* off2 = (float*)(wsb + O_OFF2);
    float* off3 = (float*)(wsb + O_OFF3);
    float* out  = (float*)d_out;

    k_prepw<<<dim3(5312), dim3(256), 0, stream>>>(
        w_b1, w_b21, w_b31, w_b4, w_cc, w_ddc2, w_ddc3, w_off2, w_off3, ws8);
    k_xpose<<<dim3(128, 16, 8), dim3(256), 0, stream>>>(x, xbT);
    k_pool<<<dim3(8192), dim3(256), 0, stream>>>(xbT, pxb);
    // b4 first (frees pxb region for t2b/t3b/offsets)
    k_gemm<<<dim3(32, 1, 8), dim3(256), 0, stream>>>(w4b, b_b4, pxb, catb, 512, 384);
    k_gemm<<<dim3(32, 1, 8), dim3(256), 0, stream>>>(wpb, b_b1, xbT, catb, 512, 0);
    k_gemm<<<dim3(32, 1, 8), dim3(256), 0, stream>>>(wpb + 128 * 512, b_b21, xbT, t2b, 128, 0);
    k_gemm<<<dim3(32, 1, 8), dim3(256), 0, stream>>>(wpb + 256 * 512, b_b31, xbT, t3b, 128, 0);
    k_offconv<3, 18><<<dim3(64, 1, 8), dim3(256), 0, stream>>>(t2b, wo2t, b_off2, off2);
    k_offconv<5, 50><<<dim3(64, 1, 8), dim3(256), 0, stream>>>(t3b, wo3t, b_off3, off3);
    k_deform3<3><<<dim3(64, 1, 8), dim3(256), 0, stream>>>(t2b, off2, wd2t, b_ddc2, catb, 128);
    k_deform3<5><<<dim3(64, 1, 8), dim3(256), 0, stream>>>(t3b, off3, wd3t, b_ddc3, catb, 256);
    k_gemm_final<<<dim3(32, 4, 8), dim3(256), 0, stream>>>(wccb, b_cc, catb, xbT, x, out);
}

// Round 4
// 657.384 us; speedup vs baseline: 4.1427x; 1.1385x over previous
//
#include <hip/hip_runtime.h>
#include <math.h>

#define HW 4096
typedef short short8 __attribute__((ext_vector_type(8)));
typedef float floatx4 __attribute__((ext_vector_type(4)));

// ---- ws layout (bytes) ----
#define O_XBT   0ull            // [8][4096][512] bf16 x NHWC
#define O_PXB   33554432ull     // [8][4096][512] bf16 pooled x NHWC (reused later)
#define O_CATB  67108864ull     // [8][4096][512] bf16 cat branches NHWC
#define O_WPB   100663296ull    // [384][512] bf16
#define O_W4B   101056512ull    // [128][512] bf16
#define O_WCCB  101187584ull    // [512][512] bf16
#define O_WD2T  101711872ull    // [9][128][128] bf16
#define O_WD3T  102006784ull    // [25][128][128] bf16
#define O_WO2T  102825984ull    // [9][64][128] bf16
#define O_WO3T  102973440ull    // [25][64][128] bf16
// reuse of PXB region after b4 GEMM:
#define O_T2B   33554432ull     // [8][4096][128] bf16 b2i NHWC
#define O_T3B   41943040ull     // [8][4096][128] bf16 b3i NHWC
#define O_OFF2  50331648ull     // [8][18][4096] f32
#define O_OFF3  52690944ull     // [8][50][4096] f32

__device__ __forceinline__ unsigned short f2b(float f) {
    union { float f; unsigned u; } v; v.f = f;
    unsigned r = v.u + 0x7FFFu + ((v.u >> 16) & 1u);
    return (unsigned short)(r >> 16);
}
__device__ __forceinline__ float lou(unsigned u) {
    union { unsigned u; float f; } v; v.u = u << 16; return v.f;
}
__device__ __forceinline__ float hiu(unsigned u) {
    union { unsigned u; float f; } v; v.u = u & 0xFFFF0000u; return v.f;
}
__device__ __forceinline__ unsigned pk2(float lo, float hi) {
    return (unsigned)f2b(lo) | ((unsigned)f2b(hi) << 16);
}

// ------------------------------------------------------------- weight prep
__global__ __launch_bounds__(256) void k_prepw(
        const float* __restrict__ w1, const float* __restrict__ w21,
        const float* __restrict__ w31, const float* __restrict__ w4,
        const float* __restrict__ wcc, const float* __restrict__ wd2,
        const float* __restrict__ wd3, const float* __restrict__ wo2,
        const float* __restrict__ wo3, unsigned short* __restrict__ ws8) {
    unsigned i = blockIdx.x * 256 + threadIdx.x;
    unsigned short* wpb  = ws8 + (O_WPB  >> 1);
    unsigned short* w4b  = ws8 + (O_W4B  >> 1);
    unsigned short* wccb = ws8 + (O_WCCB >> 1);
    unsigned short* wd2t = ws8 + (O_WD2T >> 1);
    unsigned short* wd3t = ws8 + (O_WD3T >> 1);
    unsigned short* wo2t = ws8 + (O_WO2T >> 1);
    unsigned short* wo3t = ws8 + (O_WO3T >> 1);
    if (i < 196608) {
        int o = i >> 9;
        float v = (o < 128) ? w1[i] : (o < 256) ? w21[i - 65536] : w31[i - 131072];
        wpb[i] = f2b(v);
    } else if (i < 262144) {
        unsigned j = i - 196608; w4b[j] = f2b(w4[j]);
    } else if (i < 524288) {
        unsigned j = i - 262144; wccb[j] = f2b(wcc[j]);
    } else if (i < 671744) {
        unsigned j = i - 524288; int t = j >> 14, o = (j >> 7) & 127, c = j & 127;
        wd2t[j] = f2b(wd2[((o * 128 + c) * 9) + t]);
    } else if (i < 1081344) {
        unsigned j = i - 671744; int t = j >> 14, o = (j >> 7) & 127, c = j & 127;
        wd3t[j] = f2b(wd3[((o * 128 + c) * 25) + t]);
    } else if (i < 1155072) {
        unsigned j = i - 1081344; int t = j >> 13, o = (j >> 7) & 63, c = j & 127;
        wo2t[j] = (o < 18) ? f2b(wo2[((o * 128 + c) * 9) + t]) : 0;
    } else if (i < 1359872) {
        unsigned j = i - 1155072; int t = j >> 13, o = (j >> 7) & 63, c = j & 127;
        wo3t[j] = (o < 50) ? f2b(wo3[((o * 128 + c) * 25) + t]) : 0;
    }
}

// ---------------------------------------- x NCHW f32 -> NHWC bf16 transpose
__global__ __launch_bounds__(256) void k_xpose(const float* __restrict__ X,
                                               unsigned short* __restrict__ xbT) {
    __shared__ unsigned short t[32][33];
    const int p0 = blockIdx.x * 32, c0 = blockIdx.y * 32, b = blockIdx.z;
    const int tid = threadIdx.x;
    #pragma unroll
    for (int s = 0; s < 4; ++s) {
        int cl = s * 8 + (tid >> 5), pl = tid & 31;
        t[cl][pl] = f2b(X[((size_t)b * 512 + c0 + cl) * HW + p0 + pl]);
    }
    __syncthreads();
    #pragma unroll
    for (int s = 0; s < 4; ++s) {
        int pl = s * 8 + (tid >> 5), cl = tid & 31;
        xbT[((size_t)b * HW + p0 + pl) * 512 + c0 + cl] = t[cl][pl];
    }
}

// ----------------------------------------------- 3x3 s1 maxpool on NHWC bf16
__global__ __launch_bounds__(256) void k_pool(const unsigned short* __restrict__ xbT,
                                              unsigned short* __restrict__ pxb) {
    unsigned gid = blockIdx.x * 256 + threadIdx.x;   // 8*4096*64
    int b = gid >> 18;
    unsigned rem = gid & 262143;
    int pos = rem >> 6;
    int cg = (rem & 63) * 8;
    int h = pos >> 6, w = pos & 63;
    const unsigned short* img = xbT + (size_t)b * HW * 512;
    float m[8] = {-INFINITY, -INFINITY, -INFINITY, -INFINITY,
                  -INFINITY, -INFINITY, -INFINITY, -INFINITY};
    #pragma unroll
    for (int dy = -1; dy <= 1; ++dy) {
        int hh = h + dy;
        if (hh < 0 || hh >= 64) continue;
        #pragma unroll
        for (int dx = -1; dx <= 1; ++dx) {
            int ww = w + dx;
            if (ww < 0 || ww >= 64) continue;
            uint4 v = *(const uint4*)(img + ((size_t)(hh * 64 + ww)) * 512 + cg);
            unsigned uu[4] = {v.x, v.y, v.z, v.w};
            #pragma unroll
            for (int e = 0; e < 4; ++e) {
                m[2 * e]     = fmaxf(m[2 * e],     lou(uu[e]));
                m[2 * e + 1] = fmaxf(m[2 * e + 1], hiu(uu[e]));
            }
        }
    }
    uint4 o;
    o.x = pk2(m[0], m[1]); o.y = pk2(m[2], m[3]);
    o.z = pk2(m[4], m[5]); o.w = pk2(m[6], m[7]);
    *(uint4*)(pxb + ((size_t)b * HW + pos) * 512 + cg) = o;
}

// ----------------------------- bf16 MFMA GEMM: C[128 x 128pos] = A[128x512]B
// Epilogue bounces C through LDS so global stores are 256B-contiguous runs.
#define SA(r,c) SM[(r)*40 + (c)]
#define SB(r,c) SM[5120 + (r)*40 + (c)]
#define SC(r,c) SM[(r)*136 + (c)]
__global__ __launch_bounds__(256) void k_gemm(
        const unsigned short* __restrict__ A, const float* __restrict__ bias,
        const unsigned short* __restrict__ Bm,
        unsigned short* __restrict__ dst, int dStride, int dOff) {
    __shared__ unsigned short SM[17408];
    const int tid = threadIdx.x;
    const int n0 = blockIdx.x * 128;
    const int b = blockIdx.z;
    const int wave = tid >> 6, lane = tid & 63, quad = lane >> 4, lr = lane & 15;
    const int m0w = (wave & 1) * 64, n0w = (wave >> 1) * 64;
    const int srow = tid >> 1, skh = (tid & 1) * 16;
    floatx4 acc[4][4] = {};

    for (int k0 = 0; k0 < 512; k0 += 32) {
        const unsigned short* ga = A + (size_t)srow * 512 + k0 + skh;
        uint4 a0 = *(const uint4*)(ga);
        uint4 a1 = *(const uint4*)(ga + 8);
        const unsigned short* gb = Bm + ((size_t)b * HW + n0 + srow) * 512 + k0 + skh;
        uint4 b0 = *(const uint4*)(gb);
        uint4 b1 = *(const uint4*)(gb + 8);
        __syncthreads();
        *(uint4*)&SA(srow, skh) = a0;
        *(uint4*)&SA(srow, skh + 8) = a1;
        *(uint4*)&SB(srow, skh) = b0;
        *(uint4*)&SB(srow, skh + 8) = b1;
        __syncthreads();
        short8 af[4], bf[4];
        #pragma unroll
        for (int i = 0; i < 4; ++i) af[i] = *(short8*)&SA(m0w + i * 16 + lr, quad * 8);
        #pragma unroll
        for (int j = 0; j < 4; ++j) bf[j] = *(short8*)&SB(n0w + j * 16 + lr, quad * 8);
        #pragma unroll
        for (int i = 0; i < 4; ++i)
            #pragma unroll
            for (int j = 0; j < 4; ++j)
                acc[i][j] = __builtin_amdgcn_mfma_f32_16x16x32_bf16(af[i], bf[j], acc[i][j], 0, 0, 0);
    }
    __syncthreads();
    #pragma unroll
    for (int i = 0; i < 4; ++i) {
        float4 bs = *(const float4*)&bias[m0w + i * 16 + quad * 4];
        #pragma unroll
        for (int j = 0; j < 4; ++j) {
            floatx4 v = acc[i][j];
            int pos = n0w + j * 16 + lr;
            int ch = m0w + i * 16 + quad * 4;
            uint2 st;
            st.x = pk2(v[0] + bs.x, v[1] + bs.y);
            st.y = pk2(v[2] + bs.z, v[3] + bs.w);
            *(uint2*)&SC(pos, ch) = st;
        }
    }
    __syncthreads();
    #pragma unroll
    for (int r = 0; r < 8; ++r) {
        int pos = (tid >> 4) + r * 16;
        *(uint4*)&dst[((size_t)b * HW + n0 + pos) * dStride + dOff + (tid & 15) * 8] =
            *(uint4*)&SC(pos, (tid & 15) * 8);
    }
}

// ------------------------------------ offset convs via MFMA (M=64 padded)
template<int KS, int OCH>
__global__ __launch_bounds__(256) void k_offconv(
        const unsigned short* __restrict__ img,   // [B][4096][128] bf16
        const unsigned short* __restrict__ woT,   // [TT][64][128] bf16
        const float* __restrict__ bias, float* __restrict__ Out) {
    constexpr int PAD = KS / 2;
    constexpr int TT = KS * KS;
    __shared__ unsigned short sW[64][136];
    __shared__ unsigned short sS[64][136];
    const int tid = threadIdx.x;
    const int hrow = blockIdx.x, b = blockIdx.z;
    const int wave = tid >> 6, lane = tid & 63, quad = lane >> 4, lr = lane & 15;
    const int m0w = (wave & 1) * 32, n0w = (wave >> 1) * 32;
    const int row = tid >> 2, q4 = (tid & 3) * 32;
    const unsigned short* ib = img + (size_t)b * HW * 128;
    floatx4 acc[2][2] = {};

    for (int t = 0; t < TT; ++t) {
        int ky = t / KS, kx = t % KS;
        int r = hrow + ky - PAD;
        const uint4* wsrc = (const uint4*)(woT + ((size_t)t * 64 + row) * 128 + q4);
        uint4 wv[4] = {wsrc[0], wsrc[1], wsrc[2], wsrc[3]};
        int xcol = row + kx - PAD;   // row == pos here
        uint4 sv[4] = {};
        if ((unsigned)r < 64u && (unsigned)xcol < 64u) {
            const uint4* ssrc = (const uint4*)(ib + ((size_t)(r * 64 + xcol)) * 128 + q4);
            sv[0] = ssrc[0]; sv[1] = ssrc[1]; sv[2] = ssrc[2]; sv[3] = ssrc[3];
        }
        __syncthreads();
        #pragma unroll
        for (int j = 0; j < 4; ++j) {
            *(uint4*)&sW[row][q4 + j * 8] = wv[j];
            *(uint4*)&sS[row][q4 + j * 8] = sv[j];
        }
        __syncthreads();
        #pragma unroll
        for (int ks = 0; ks < 4; ++ks) {
            short8 af[2], bf[2];
            #pragma unroll
            for (int i = 0; i < 2; ++i)
                af[i] = *(short8*)&sW[m0w + i * 16 + lr][ks * 32 + quad * 8];
            #pragma unroll
            for (int j = 0; j < 2; ++j)
                bf[j] = *(short8*)&sS[n0w + j * 16 + lr][ks * 32 + quad * 8];
            #pragma unroll
            for (int i = 0; i < 2; ++i)
                #pragma unroll
                for (int j = 0; j < 2; ++j)
                    acc[i][j] = __builtin_amdgcn_mfma_f32_16x16x32_bf16(af[i], bf[j], acc[i][j], 0, 0, 0);
        }
    }
    #pragma unroll
    for (int i = 0; i < 2; ++i) {
        #pragma unroll
        for (int j = 0; j < 2; ++j) {
            floatx4 v = acc[i][j];
            int col = n0w + j * 16 + lr;
            #pragma unroll
            for (int rg = 0; rg < 4; ++rg) {
                int o = m0w + i * 16 + quad * 4 + rg;
                if (o < OCH)
                    Out[((size_t)b * OCH + o) * HW + hrow * 64 + col] = v[rg] + bias[o];
            }
        }
    }
}

// ---------------------- deformable conv via MFMA, 128pos x 128o, 512 threads
template<int KS>
__global__ __launch_bounds__(512) void k_deform4(
        const unsigned short* __restrict__ img,   // [B][4096][128] bf16
        const float* __restrict__ Off,            // [B][2TT][4096] f32
        const unsigned short* __restrict__ wdT,   // [TT][128][128] bf16
        const float* __restrict__ bias,
        unsigned short* __restrict__ catb, int dOff) {
    constexpr int PAD = KS / 2;
    constexpr int TT = KS * KS;
    __shared__ unsigned short sW[128][136];
    __shared__ unsigned short sS[128][136];
    const int tid = threadIdx.x;
    const int hrow0 = blockIdx.x * 2, b = blockIdx.z;
    const int wave = tid >> 6, lane = tid & 63, quad = lane >> 4, lr = lane & 15;
    const int m0w = (wave & 1) * 64, n0w = (wave >> 1) * 32;
    const int pos = tid >> 2, cq = (tid & 3) * 32;
    const int pglob = blockIdx.x * 128 + pos;
    const int h = hrow0 + (pos >> 6), w = pos & 63;
    const unsigned short* ib = img + (size_t)b * HW * 128;
    const float* offb = Off + (size_t)b * 2 * TT * HW;
    floatx4 acc[4][2] = {};

    for (int t = 0; t < TT; ++t) {
        float dy = offb[(size_t)(2 * t) * HW + pglob];
        float dx = offb[(size_t)(2 * t + 1) * HW + pglob];
        float fy = (float)(h + t / KS - PAD) + dy;
        float fx = (float)(w + t % KS - PAD) + dx;
        float y0f = floorf(fy), x0f = floorf(fx);
        float wy = fy - y0f, wx = fx - x0f;
        int y0 = (int)y0f, x0 = (int)x0f;
        float w00 = (1.f - wy) * (1.f - wx), w01 = (1.f - wy) * wx;
        float w10 = wy * (1.f - wx), w11 = wy * wx;
        // weight tile loads: 32KB over 512 threads = 64 B each
        const uint4* wsrc = (const uint4*)(wdT + ((size_t)t * 128 + (tid >> 2)) * 128 + cq);
        uint4 wv[4] = {wsrc[0], wsrc[1], wsrc[2], wsrc[3]};
        // corner loads (32 channels per thread)
        bool yv0 = (unsigned)y0 < 64u, yv1 = (unsigned)(y0 + 1) < 64u;
        bool xv0 = (unsigned)x0 < 64u, xv1 = (unsigned)(x0 + 1) < 64u;
        uint4 cA[4] = {}, cB[4] = {}, cC[4] = {}, cD[4] = {};
        long bidx = (long)(y0 * 64 + x0) * 128 + cq;
        if (yv0 && xv0) { const uint4* p = (const uint4*)(ib + bidx);
            cA[0]=p[0]; cA[1]=p[1]; cA[2]=p[2]; cA[3]=p[3]; }
        if (yv0 && xv1) { const uint4* p = (const uint4*)(ib + bidx + 128);
            cB[0]=p[0]; cB[1]=p[1]; cB[2]=p[2]; cB[3]=p[3]; }
        if (yv1 && xv0) { const uint4* p = (const uint4*)(ib + bidx + 64 * 128);
            cC[0]=p[0]; cC[1]=p[1]; cC[2]=p[2]; cC[3]=p[3]; }
        if (yv1 && xv1) { const uint4* p = (const uint4*)(ib + bidx + 65 * 128);
            cD[0]=p[0]; cD[1]=p[1]; cD[2]=p[2]; cD[3]=p[3]; }
        uint4 outv[4];
        #pragma unroll
        for (int j = 0; j < 4; ++j) {
            unsigned a[4] = {cA[j].x, cA[j].y, cA[j].z, cA[j].w};
            unsigned bb[4] = {cB[j].x, cB[j].y, cB[j].z, cB[j].w};
            unsigned c[4] = {cC[j].x, cC[j].y, cC[j].z, cC[j].w};
            unsigned d[4] = {cD[j].x, cD[j].y, cD[j].z, cD[j].w};
            unsigned r[4];
            #pragma unroll
            for (int e = 0; e < 4; ++e) {
                float lo = w00 * lou(a[e]) + w01 * lou(bb[e]) + w10 * lou(c[e]) + w11 * lou(d[e]);
                float hi = w00 * hiu(a[e]) + w01 * hiu(bb[e]) + w10 * hiu(c[e]) + w11 * hiu(d[e]);
                r[e] = pk2(lo, hi);
            }
            outv[j].x = r[0]; outv[j].y = r[1]; outv[j].z = r[2]; outv[j].w = r[3];
        }
        __syncthreads();
        #pragma unroll
        for (int j = 0; j < 4; ++j) {
            *(uint4*)&sW[tid >> 2][cq + j * 8] = wv[j];
            *(uint4*)&sS[pos][cq + j * 8] = outv[j];
        }
        __syncthreads();
        #pragma unroll
        for (int ks = 0; ks < 4; ++ks) {
            short8 af[4], bf[2];
            #pragma unroll
            for (int i = 0; i < 4; ++i)
                af[i] = *(short8*)&sW[m0w + i * 16 + lr][ks * 32 + quad * 8];
            #pragma unroll
            for (int j = 0; j < 2; ++j)
                bf[j] = *(short8*)&sS[n0w + j * 16 + lr][ks * 32 + quad * 8];
            #pragma unroll
            for (int i = 0; i < 4; ++i)
                #pragma unroll
                for (int j = 0; j < 2; ++j)
                    acc[i][j] = __builtin_amdgcn_mfma_f32_16x16x32_bf16(af[i], bf[j], acc[i][j], 0, 0, 0);
        }
    }
    // epilogue: stage C into sW (as [pos][ch]) then contiguous stores
    __syncthreads();
    #pragma unroll
    for (int i = 0; i < 4; ++i) {
        float4 bs = *(const float4*)&bias[m0w + i * 16 + quad * 4];
        #pragma unroll
        for (int j = 0; j < 2; ++j) {
            floatx4 v = acc[i][j];
            int p = n0w + j * 16 + lr;
            int ch = m0w + i * 16 + quad * 4;
            uint2 st;
            st.x = pk2(v[0] + bs.x, v[1] + bs.y);
            st.y = pk2(v[2] + bs.z, v[3] + bs.w);
            *(uint2*)&sW[p][ch] = st;
        }
    }
    __syncthreads();
    #pragma unroll
    for (int r = 0; r < 4; ++r) {
        int p = (tid >> 4) + r * 32;
        *(uint4*)&catb[((size_t)b * HW + blockIdx.x * 128 + p) * 512 + dOff + (tid & 15) * 8] =
            *(uint4*)&sW[p][(tid & 15) * 8];
    }
}

// ------------------- final: sigmoid(Wcc @ (catb*xbT)) + x, fp32 NCHW output
__global__ __launch_bounds__(256) void k_gemm_final(
        const unsigned short* __restrict__ A, const float* __restrict__ bias,
        const unsigned short* __restrict__ catb, const unsigned short* __restrict__ xbT,
        const float* __restrict__ X, float* __restrict__ OutF) {
    __shared__ unsigned short sA[128][40];
    __shared__ unsigned short sB[128][40];
    const int tid = threadIdx.x;
    const int n0 = blockIdx.x * 128;
    const int o0 = blockIdx.y * 128;
    const int b = blockIdx.z;
    const int wave = tid >> 6, lane = tid & 63, quad = lane >> 4, lr = lane & 15;
    const int m0w = (wave & 1) * 64, n0w = (wave >> 1) * 64;
    const int srow = tid >> 1, skh = (tid & 1) * 16;
    floatx4 acc[4][4] = {};

    for (int k0 = 0; k0 < 512; k0 += 32) {
        const unsigned short* ga = A + (size_t)(o0 + srow) * 512 + k0 + skh;
        uint4 a0 = *(const uint4*)(ga);
        uint4 a1 = *(const uint4*)(ga + 8);
        size_t bi = ((size_t)b * HW + n0 + srow) * 512 + k0 + skh;
        uint4 c0 = *(const uint4*)(catb + bi);
        uint4 c1 = *(const uint4*)(catb + bi + 8);
        uint4 x0 = *(const uint4*)(xbT + bi);
        uint4 x1 = *(const uint4*)(xbT + bi + 8);
        unsigned cu[8] = {c0.x, c0.y, c0.z, c0.w, c1.x, c1.y, c1.z, c1.w};
        unsigned xu[8] = {x0.x, x0.y, x0.z, x0.w, x1.x, x1.y, x1.z, x1.w};
        unsigned mu[8];
        #pragma unroll
        for (int e = 0; e < 8; ++e)
            mu[e] = pk2(lou(cu[e]) * lou(xu[e]), hiu(cu[e]) * hiu(xu[e]));
        __syncthreads();
        *(uint4*)&sA[srow][skh] = a0;
        *(uint4*)&sA[srow][skh + 8] = a1;
        uint4 m0v; m0v.x = mu[0]; m0v.y = mu[1]; m0v.z = mu[2]; m0v.w = mu[3];
        uint4 m1v; m1v.x = mu[4]; m1v.y = mu[5]; m1v.z = mu[6]; m1v.w = mu[7];
        *(uint4*)&sB[srow][skh] = m0v;
        *(uint4*)&sB[srow][skh + 8] = m1v;
        __syncthreads();
        short8 af[4], bf[4];
        #pragma unroll
        for (int i = 0; i < 4; ++i) af[i] = *(short8*)&sA[m0w + i * 16 + lr][quad * 8];
        #pragma unroll
        for (int j = 0; j < 4; ++j) bf[j] = *(short8*)&sB[n0w + j * 16 + lr][quad * 8];
        #pragma unroll
        for (int i = 0; i < 4; ++i)
            #pragma unroll
            for (int j = 0; j < 4; ++j)
                acc[i][j] = __builtin_amdgcn_mfma_f32_16x16x32_bf16(af[i], bf[j], acc[i][j], 0, 0, 0);
    }
    #pragma unroll
    for (int i = 0; i < 4; ++i) {
        float4 bs = *(const float4*)&bias[o0 + m0w + i * 16 + quad * 4];
        float bsa[4] = {bs.x, bs.y, bs.z, bs.w};
        #pragma unroll
        for (int j = 0; j < 4; ++j) {
            floatx4 v = acc[i][j];
            int pos = n0 + n0w + j * 16 + lr;
            #pragma unroll
            for (int rg = 0; rg < 4; ++rg) {
                int o = o0 + m0w + i * 16 + quad * 4 + rg;
                float f = v[rg] + bsa[rg];
                float sg = 1.f / (1.f + __expf(-f));
                size_t idx = ((size_t)b * 512 + o) * HW + pos;
                OutF[idx] = X[idx] + sg;
            }
        }
    }
}

// ------------------------------------------------------------------- launcher
extern "C" void kernel_launch(void* const* d_in, const int* in_sizes, int n_in,
                              void* d_out, int out_size, void* d_ws, size_t ws_size,
                              hipStream_t stream) {
    const float* x      = (const float*)d_in[0];
    const float* w_b1   = (const float*)d_in[1];
    const float* b_b1   = (const float*)d_in[2];
    const float* w_b21  = (const float*)d_in[3];
    const float* b_b21  = (const float*)d_in[4];
    const float* w_off2 = (const float*)d_in[5];
    const float* b_off2 = (const float*)d_in[6];
    const float* w_ddc2 = (const float*)d_in[7];
    const float* b_ddc2 = (const float*)d_in[8];
    const float* w_b31  = (const float*)d_in[9];
    const float* b_b31  = (const float*)d_in[10];
    const float* w_off3 = (const float*)d_in[11];
    const float* b_off3 = (const float*)d_in[12];
    const float* w_ddc3 = (const float*)d_in[13];
    const float* b_ddc3 = (const float*)d_in[14];
    const float* w_b4   = (const float*)d_in[15];
    const float* b_b4   = (const float*)d_in[16];
    const float* w_cc   = (const float*)d_in[17];
    const float* b_cc   = (const float*)d_in[18];

    char* wsb = (char*)d_ws;
    unsigned short* ws8  = (unsigned short*)d_ws;
    unsigned short* xbT  = (unsigned short*)(wsb + O_XBT);
    unsigned short* pxb  = (unsigned short*)(wsb + O_PXB);
    unsigned short* catb = (unsigned short*)(wsb + O_CATB);
    unsigned short* wpb  = (unsigned short*)(wsb + O_WPB);
    unsigned short* w4b  = (unsigned short*)(wsb + O_W4B);
    unsigned short* wccb = (unsigned short*)(wsb + O_WCCB);
    unsigned short* wd2t = (unsigned short*)(wsb + O_WD2T);
    unsigned short* wd3t = (unsigned short*)(wsb + O_WD3T);
    unsigned short* wo2t = (unsigned short*)(wsb + O_WO2T);
    unsigned short* wo3t = (unsigned short*)(wsb + O_WO3T);
    unsigned short* t2b  = (unsigned short*)(wsb + O_T2B);
    unsigned short* t3b  = (unsigned short*)(wsb + O_T3B);
    float* off2 = (float*)(wsb + O_OFF2);
    float* off3 = (float*)(wsb + O_OFF3);
    float* out  = (float*)d_out;

    k_prepw<<<dim3(5312), dim3(256), 0, stream>>>(
        w_b1, w_b21, w_b31, w_b4, w_cc, w_ddc2, w_ddc3, w_off2, w_off3, ws8);
    k_xpose<<<dim3(128, 16, 8), dim3(256), 0, stream>>>(x, xbT);
    k_pool<<<dim3(8192), dim3(256), 0, stream>>>(xbT, pxb);
    // b4 first (frees pxb region for t2b/t3b/offsets)
    k_gemm<<<dim3(32, 1, 8), dim3(256), 0, stream>>>(w4b, b_b4, pxb, catb, 512, 384);
    k_gemm<<<dim3(32, 1, 8), dim3(256), 0, stream>>>(wpb, b_b1, xbT, catb, 512, 0);
    k_gemm<<<dim3(32, 1, 8), dim3(256), 0, stream>>>(wpb + 128 * 512, b_b21, xbT, t2b, 128, 0);
    k_gemm<<<dim3(32, 1, 8), dim3(256), 0, stream>>>(wpb + 256 * 512, b_b31, xbT, t3b, 128, 0);
    k_offconv<3, 18><<<dim3(64, 1, 8), dim3(256), 0, stream>>>(t2b, wo2t, b_off2, off2);
    k_offconv<5, 50><<<dim3(64, 1, 8), dim3(256), 0, stream>>>(t3b, wo3t, b_off3, off3);
    k_deform4<3><<<dim3(32, 1, 8), dim3(512), 0, stream>>>(t2b, off2, wd2t, b_ddc2, catb, 128);
    k_deform4<5><<<dim3(32, 1, 8), dim3(512), 0, stream>>>(t3b, off3, wd3t, b_ddc3, catb, 256);
    k_gemm_final<<<dim3(32, 4, 8), dim3(256), 0, stream>>>(wccb, b_cc, catb, xbT, x, out);
}

// Round 5
// 550.792 us; speedup vs baseline: 4.9444x; 1.1935x over previous
//
#include <hip/hip_runtime.h>
#include <math.h>

#define HW 4096
typedef short short8 __attribute__((ext_vector_type(8)));
typedef float floatx4 __attribute__((ext_vector_type(4)));

// ---- ws layout (bytes) ----
#define O_XBT   0ull            // [8][4096][512] bf16 x NHWC
#define O_PXB   33554432ull     // [8][4096][512] bf16 pooled x NHWC (reused later)
#define O_CATB  67108864ull     // [8][4096][512] bf16 cat branches NHWC
#define O_WPB   100663296ull    // [384][512] bf16
#define O_W4B   101056512ull    // [128][512] bf16
#define O_WCCB  101187584ull    // [512][512] bf16
#define O_WD2T  101711872ull    // [9][128][128] bf16 (t,c,o)
#define O_WD3T  102006784ull    // [25][128][128] bf16 (t,c,o)
#define O_WO2T  102825984ull    // [9][64][128] bf16 (t,o,c)
#define O_WO3T  102973440ull    // [25][64][128] bf16 (t,o,c)
// reuse of PXB region after b4 GEMM:
#define O_T2B   33554432ull     // [8][4096][128] bf16 b2i NHWC
#define O_T3B   41943040ull     // [8][4096][128] bf16 b3i NHWC
#define O_OFF2  50331648ull     // [8][18][4096] f32
#define O_OFF3  52690944ull     // [8][50][4096] f32

__device__ __forceinline__ unsigned short f2b(float f) {
    union { float f; unsigned u; } v; v.f = f;
    unsigned r = v.u + 0x7FFFu + ((v.u >> 16) & 1u);
    return (unsigned short)(r >> 16);
}
__device__ __forceinline__ float lou(unsigned u) {
    union { unsigned u; float f; } v; v.u = u << 16; return v.f;
}
__device__ __forceinline__ float hiu(unsigned u) {
    union { unsigned u; float f; } v; v.u = u & 0xFFFF0000u; return v.f;
}
__device__ __forceinline__ unsigned pk2(float lo, float hi) {
    return (unsigned)f2b(lo) | ((unsigned)f2b(hi) << 16);
}

// ------------------------------------------------------------- weight prep
__global__ __launch_bounds__(256) void k_prepw(
        const float* __restrict__ w1, const float* __restrict__ w21,
        const float* __restrict__ w31, const float* __restrict__ w4,
        const float* __restrict__ wcc, const float* __restrict__ wd2,
        const float* __restrict__ wd3, const float* __restrict__ wo2,
        const float* __restrict__ wo3, unsigned short* __restrict__ ws8) {
    unsigned i = blockIdx.x * 256 + threadIdx.x;
    unsigned short* wpb  = ws8 + (O_WPB  >> 1);
    unsigned short* w4b  = ws8 + (O_W4B  >> 1);
    unsigned short* wccb = ws8 + (O_WCCB >> 1);
    unsigned short* wd2t = ws8 + (O_WD2T >> 1);
    unsigned short* wd3t = ws8 + (O_WD3T >> 1);
    unsigned short* wo2t = ws8 + (O_WO2T >> 1);
    unsigned short* wo3t = ws8 + (O_WO3T >> 1);
    if (i < 196608) {
        int o = i >> 9;
        float v = (o < 128) ? w1[i] : (o < 256) ? w21[i - 65536] : w31[i - 131072];
        wpb[i] = f2b(v);
    } else if (i < 262144) {
        unsigned j = i - 196608; w4b[j] = f2b(w4[j]);
    } else if (i < 524288) {
        unsigned j = i - 262144; wccb[j] = f2b(wcc[j]);
    } else if (i < 671744) {
        unsigned j = i - 524288; int t = j >> 14, o = (j >> 7) & 127, c = j & 127;
        wd2t[j] = f2b(wd2[((o * 128 + c) * 9) + t]);
    } else if (i < 1081344) {
        unsigned j = i - 671744; int t = j >> 14, o = (j >> 7) & 127, c = j & 127;
        wd3t[j] = f2b(wd3[((o * 128 + c) * 25) + t]);
    } else if (i < 1155072) {
        // layout (t, o, c): j = (t*64 + o)*128 + c
        unsigned j = i - 1081344; int t = j >> 13, o = (j >> 7) & 63, c = j & 127;
        wo2t[j] = (o < 18) ? f2b(wo2[((o * 128 + c) * 9) + t]) : 0;
    } else if (i < 1359872) {
        unsigned j = i - 1155072; int t = j >> 13, o = (j >> 7) & 63, c = j & 127;
        wo3t[j] = (o < 50) ? f2b(wo3[((o * 128 + c) * 25) + t]) : 0;
    }
}

// ---------------------------------------- x NCHW f32 -> NHWC bf16 transpose
__global__ __launch_bounds__(256) void k_xpose(const float* __restrict__ X,
                                               unsigned short* __restrict__ xbT) {
    __shared__ unsigned short t[32][33];
    const int p0 = blockIdx.x * 32, c0 = blockIdx.y * 32, b = blockIdx.z;
    const int tid = threadIdx.x;
    #pragma unroll
    for (int s = 0; s < 4; ++s) {
        int cl = s * 8 + (tid >> 5), pl = tid & 31;
        t[cl][pl] = f2b(X[((size_t)b * 512 + c0 + cl) * HW + p0 + pl]);
    }
    __syncthreads();
    #pragma unroll
    for (int s = 0; s < 4; ++s) {
        int pl = s * 8 + (tid >> 5), cl = tid & 31;
        xbT[((size_t)b * HW + p0 + pl) * 512 + c0 + cl] = t[cl][pl];
    }
}

// ----------------------------------------------- 3x3 s1 maxpool on NHWC bf16
__global__ __launch_bounds__(256) void k_pool(const unsigned short* __restrict__ xbT,
                                              unsigned short* __restrict__ pxb) {
    unsigned gid = blockIdx.x * 256 + threadIdx.x;   // 8*4096*64
    int b = gid >> 18;
    unsigned rem = gid & 262143;
    int pos = rem >> 6;
    int cg = (rem & 63) * 8;
    int h = pos >> 6, w = pos & 63;
    const unsigned short* img = xbT + (size_t)b * HW * 512;
    float m[8] = {-INFINITY, -INFINITY, -INFINITY, -INFINITY,
                  -INFINITY, -INFINITY, -INFINITY, -INFINITY};
    #pragma unroll
    for (int dy = -1; dy <= 1; ++dy) {
        int hh = h + dy;
        if (hh < 0 || hh >= 64) continue;
        #pragma unroll
        for (int dx = -1; dx <= 1; ++dx) {
            int ww = w + dx;
            if (ww < 0 || ww >= 64) continue;
            uint4 v = *(const uint4*)(img + ((size_t)(hh * 64 + ww)) * 512 + cg);
            unsigned uu[4] = {v.x, v.y, v.z, v.w};
            #pragma unroll
            for (int e = 0; e < 4; ++e) {
                m[2 * e]     = fmaxf(m[2 * e],     lou(uu[e]));
                m[2 * e + 1] = fmaxf(m[2 * e + 1], hiu(uu[e]));
            }
        }
    }
    uint4 o;
    o.x = pk2(m[0], m[1]); o.y = pk2(m[2], m[3]);
    o.z = pk2(m[4], m[5]); o.w = pk2(m[6], m[7]);
    *(uint4*)(pxb + ((size_t)b * HW + pos) * 512 + cg) = o;
}

// ----------------------------- bf16 MFMA GEMM: C[128 x 128pos] = A[128x512]B
#define SA(r,c) SM[(r)*40 + (c)]
#define SB(r,c) SM[5120 + (r)*40 + (c)]
#define SC(r,c) SM[(r)*136 + (c)]
__global__ __launch_bounds__(256) void k_gemm(
        const unsigned short* __restrict__ A, const float* __restrict__ bias,
        const unsigned short* __restrict__ Bm,
        unsigned short* __restrict__ dst, int dStride, int dOff) {
    __shared__ unsigned short SM[17408];
    const int tid = threadIdx.x;
    const int n0 = blockIdx.x * 128;
    const int b = blockIdx.z;
    const int wave = tid >> 6, lane = tid & 63, quad = lane >> 4, lr = lane & 15;
    const int m0w = (wave & 1) * 64, n0w = (wave >> 1) * 64;
    const int srow = tid >> 1, skh = (tid & 1) * 16;
    floatx4 acc[4][4] = {};

    for (int k0 = 0; k0 < 512; k0 += 32) {
        const unsigned short* ga = A + (size_t)srow * 512 + k0 + skh;
        uint4 a0 = *(const uint4*)(ga);
        uint4 a1 = *(const uint4*)(ga + 8);
        const unsigned short* gb = Bm + ((size_t)b * HW + n0 + srow) * 512 + k0 + skh;
        uint4 b0 = *(const uint4*)(gb);
        uint4 b1 = *(const uint4*)(gb + 8);
        __syncthreads();
        *(uint4*)&SA(srow, skh) = a0;
        *(uint4*)&SA(srow, skh + 8) = a1;
        *(uint4*)&SB(srow, skh) = b0;
        *(uint4*)&SB(srow, skh + 8) = b1;
        __syncthreads();
        short8 af[4], bf[4];
        #pragma unroll
        for (int i = 0; i < 4; ++i) af[i] = *(short8*)&SA(m0w + i * 16 + lr, quad * 8);
        #pragma unroll
        for (int j = 0; j < 4; ++j) bf[j] = *(short8*)&SB(n0w + j * 16 + lr, quad * 8);
        #pragma unroll
        for (int i = 0; i < 4; ++i)
            #pragma unroll
            for (int j = 0; j < 4; ++j)
                acc[i][j] = __builtin_amdgcn_mfma_f32_16x16x32_bf16(af[i], bf[j], acc[i][j], 0, 0, 0);
    }
    __syncthreads();
    #pragma unroll
    for (int i = 0; i < 4; ++i) {
        float4 bs = *(const float4*)&bias[m0w + i * 16 + quad * 4];
        #pragma unroll
        for (int j = 0; j < 4; ++j) {
            floatx4 v = acc[i][j];
            int pos = n0w + j * 16 + lr;
            int ch = m0w + i * 16 + quad * 4;
            uint2 st;
            st.x = pk2(v[0] + bs.x, v[1] + bs.y);
            st.y = pk2(v[2] + bs.z, v[3] + bs.w);
            *(uint2*)&SC(pos, ch) = st;
        }
    }
    __syncthreads();
    #pragma unroll
    for (int r = 0; r < 8; ++r) {
        int pos = (tid >> 4) + r * 16;
        *(uint4*)&dst[((size_t)b * HW + n0 + pos) * dStride + dOff + (tid & 15) * 8] =
            *(uint4*)&SC(pos, (tid & 15) * 8);
    }
}

// ---------------- offset convs v2: slab-staged, barrier-free tap loop
// block = 128 positions (2 h-rows) x 64 M (padded), 512 threads.
template<int KS, int OCH>
__global__ __launch_bounds__(512) void k_offconv2(
        const unsigned short* __restrict__ img,   // [B][4096][128] bf16
        const unsigned short* __restrict__ woT,   // [TT][64][128] bf16 (t,o,c)
        const float* __restrict__ bias, float* __restrict__ Out) {
    constexpr int PAD = KS / 2;
    constexpr int TT = KS * KS;
    constexpr int SR = 2 + 2 * PAD;
    constexpr int SC2 = 64 + 2 * PAD;
    constexpr int NE = SR * SC2;              // slab entries
    __shared__ unsigned short slab[NE * 36];  // [entry][36] (32 ch + pad)
    __shared__ float ctile[64 * 132];
    const int tid = threadIdx.x;
    const int p0 = blockIdx.x * 128, hrow0 = blockIdx.x * 2, b = blockIdx.z;
    const int wave = tid >> 6, lane = tid & 63, quad = lane >> 4, lr = lane & 15;
    const int wm = wave & 1, wn = wave >> 1;   // 2 x 4 wave grid: 32o x 32pos
    const unsigned short* ib = img + (size_t)b * HW * 128;
    floatx4 acc[2][2] = {};

    for (int c0 = 0; c0 < 128; c0 += 32) {
        __syncthreads();
        if (tid < NE) {
            int s = tid / SC2, cl = tid % SC2;
            int r = hrow0 - PAD + s, cc = cl - PAD;
            uint4 v0 = {}, v1 = {}, v2 = {}, v3 = {};
            if ((unsigned)r < 64u && (unsigned)cc < 64u) {
                const uint4* g = (const uint4*)(ib + ((size_t)(r * 64 + cc)) * 128 + c0);
                v0 = g[0]; v1 = g[1]; v2 = g[2]; v3 = g[3];
            }
            uint2* d2 = (uint2*)&slab[tid * 36];
            d2[0] = make_uint2(v0.x, v0.y); d2[1] = make_uint2(v0.z, v0.w);
            d2[2] = make_uint2(v1.x, v1.y); d2[3] = make_uint2(v1.z, v1.w);
            d2[4] = make_uint2(v2.x, v2.y); d2[5] = make_uint2(v2.z, v2.w);
            d2[6] = make_uint2(v3.x, v3.y); d2[7] = make_uint2(v3.z, v3.w);
        }
        __syncthreads();
        #pragma unroll
        for (int t = 0; t < TT; ++t) {
            const int ky = t / KS, kx = t % KS;
            short8 af[2], bf[2];
            #pragma unroll
            for (int i = 0; i < 2; ++i)
                af[i] = *(const short8*)&woT[((size_t)t * 64 + wm * 32 + i * 16 + lr) * 128
                                             + c0 + quad * 8];
            #pragma unroll
            for (int j = 0; j < 2; ++j) {
                int p = wn * 32 + j * 16 + lr;
                int e = ((p >> 6) + ky) * SC2 + (p & 63) + kx;
                union { uint2 u[2]; short8 s; } bb;
                const uint2* sp = (const uint2*)&slab[e * 36 + quad * 8];
                bb.u[0] = sp[0]; bb.u[1] = sp[1];
                bf[j] = bb.s;
            }
            #pragma unroll
            for (int i = 0; i < 2; ++i)
                #pragma unroll
                for (int j = 0; j < 2; ++j)
                    acc[i][j] = __builtin_amdgcn_mfma_f32_16x16x32_bf16(af[i], bf[j], acc[i][j], 0, 0, 0);
        }
    }
    __syncthreads();
    #pragma unroll
    for (int i = 0; i < 2; ++i)
        #pragma unroll
        for (int j = 0; j < 2; ++j) {
            floatx4 v = acc[i][j];
            int p = wn * 32 + j * 16 + lr;
            int o = wm * 32 + i * 16 + quad * 4;
            #pragma unroll
            for (int rg = 0; rg < 4; ++rg)
                ctile[(o + rg) * 132 + p] = v[rg];
        }
    __syncthreads();
    {
        int o = tid >> 3, seg = tid & 7;
        if (o < OCH) {
            float bs = bias[o];
            const float* src = &ctile[o * 132 + seg * 16];
            float* dst = &Out[((size_t)b * OCH + o) * HW + p0 + seg * 16];
            #pragma unroll
            for (int q = 0; q < 4; ++q) {
                float4 v = *(const float4*)(src + q * 4);
                v.x += bs; v.y += bs; v.z += bs; v.w += bs;
                *(float4*)(dst + q * 4) = v;
            }
        }
    }
}

// ---------------------- deformable conv via MFMA, 128pos x 128o, 512 threads
template<int KS>
__global__ __launch_bounds__(512) void k_deform4(
        const unsigned short* __restrict__ img,   // [B][4096][128] bf16
        const float* __restrict__ Off,            // [B][2TT][4096] f32
        const unsigned short* __restrict__ wdT,   // [TT][128][128] bf16 (t,c,o)
        const float* __restrict__ bias,
        unsigned short* __restrict__ catb, int dOff) {
    constexpr int PAD = KS / 2;
    constexpr int TT = KS * KS;
    __shared__ unsigned short sW[128][136];
    __shared__ unsigned short sS[128][136];
    const int tid = threadIdx.x;
    const int hrow0 = blockIdx.x * 2, b = blockIdx.z;
    const int wave = tid >> 6, lane = tid & 63, quad = lane >> 4, lr = lane & 15;
    const int m0w = (wave & 1) * 64, n0w = (wave >> 1) * 32;
    const int pos = tid >> 2, cq = (tid & 3) * 32;
    const int pglob = blockIdx.x * 128 + pos;
    const int h = hrow0 + (pos >> 6), w = pos & 63;
    const unsigned short* ib = img + (size_t)b * HW * 128;
    const float* offb = Off + (size_t)b * 2 * TT * HW;
    floatx4 acc[4][2] = {};

    for (int t = 0; t < TT; ++t) {
        float dy = offb[(size_t)(2 * t) * HW + pglob];
        float dx = offb[(size_t)(2 * t + 1) * HW + pglob];
        float fy = (float)(h + t / KS - PAD) + dy;
        float fx = (float)(w + t % KS - PAD) + dx;
        float y0f = floorf(fy), x0f = floorf(fx);
        float wy = fy - y0f, wx = fx - x0f;
        int y0 = (int)y0f, x0 = (int)x0f;
        float w00 = (1.f - wy) * (1.f - wx), w01 = (1.f - wy) * wx;
        float w10 = wy * (1.f - wx), w11 = wy * wx;
        const uint4* wsrc = (const uint4*)(wdT + ((size_t)t * 128 + (tid >> 2)) * 128 + cq);
        uint4 wv[4] = {wsrc[0], wsrc[1], wsrc[2], wsrc[3]};
        bool yv0 = (unsigned)y0 < 64u, yv1 = (unsigned)(y0 + 1) < 64u;
        bool xv0 = (unsigned)x0 < 64u, xv1 = (unsigned)(x0 + 1) < 64u;
        uint4 cA[4] = {}, cB[4] = {}, cC[4] = {}, cD[4] = {};
        long bidx = (long)(y0 * 64 + x0) * 128 + cq;
        if (yv0 && xv0) { const uint4* p = (const uint4*)(ib + bidx);
            cA[0]=p[0]; cA[1]=p[1]; cA[2]=p[2]; cA[3]=p[3]; }
        if (yv0 && xv1) { const uint4* p = (const uint4*)(ib + bidx + 128);
            cB[0]=p[0]; cB[1]=p[1]; cB[2]=p[2]; cB[3]=p[3]; }
        if (yv1 && xv0) { const uint4* p = (const uint4*)(ib + bidx + 64 * 128);
            cC[0]=p[0]; cC[1]=p[1]; cC[2]=p[2]; cC[3]=p[3]; }
        if (yv1 && xv1) { const uint4* p = (const uint4*)(ib + bidx + 65 * 128);
            cD[0]=p[0]; cD[1]=p[1]; cD[2]=p[2]; cD[3]=p[3]; }
        uint4 outv[4];
        #pragma unroll
        for (int j = 0; j < 4; ++j) {
            unsigned a[4] = {cA[j].x, cA[j].y, cA[j].z, cA[j].w};
            unsigned bb[4] = {cB[j].x, cB[j].y, cB[j].z, cB[j].w};
            unsigned c[4] = {cC[j].x, cC[j].y, cC[j].z, cC[j].w};
            unsigned d[4] = {cD[j].x, cD[j].y, cD[j].z, cD[j].w};
            unsigned r[4];
            #pragma unroll
            for (int e = 0; e < 4; ++e) {
                float lo = w00 * lou(a[e]) + w01 * lou(bb[e]) + w10 * lou(c[e]) + w11 * lou(d[e]);
                float hi = w00 * hiu(a[e]) + w01 * hiu(bb[e]) + w10 * hiu(c[e]) + w11 * hiu(d[e]);
                r[e] = pk2(lo, hi);
            }
            outv[j].x = r[0]; outv[j].y = r[1]; outv[j].z = r[2]; outv[j].w = r[3];
        }
        __syncthreads();
        #pragma unroll
        for (int j = 0; j < 4; ++j) {
            *(uint4*)&sW[tid >> 2][cq + j * 8] = wv[j];
            *(uint4*)&sS[pos][cq + j * 8] = outv[j];
        }
        __syncthreads();
        #pragma unroll
        for (int ks = 0; ks < 4; ++ks) {
            short8 af[4], bf[2];
            #pragma unroll
            for (int i = 0; i < 4; ++i)
                af[i] = *(short8*)&sW[m0w + i * 16 + lr][ks * 32 + quad * 8];
            #pragma unroll
            for (int j = 0; j < 2; ++j)
                bf[j] = *(short8*)&sS[n0w + j * 16 + lr][ks * 32 + quad * 8];
            #pragma unroll
            for (int i = 0; i < 4; ++i)
                #pragma unroll
                for (int j = 0; j < 2; ++j)
                    acc[i][j] = __builtin_amdgcn_mfma_f32_16x16x32_bf16(af[i], bf[j], acc[i][j], 0, 0, 0);
        }
    }
    __syncthreads();
    #pragma unroll
    for (int i = 0; i < 4; ++i) {
        float4 bs = *(const float4*)&bias[m0w + i * 16 + quad * 4];
        #pragma unroll
        for (int j = 0; j < 2; ++j) {
            floatx4 v = acc[i][j];
            int p = n0w + j * 16 + lr;
            int ch = m0w + i * 16 + quad * 4;
            uint2 st;
            st.x = pk2(v[0] + bs.x, v[1] + bs.y);
            st.y = pk2(v[2] + bs.z, v[3] + bs.w);
            *(uint2*)&sW[p][ch] = st;
        }
    }
    __syncthreads();
    #pragma unroll
    for (int r = 0; r < 4; ++r) {
        int p = (tid >> 4) + r * 32;
        *(uint4*)&catb[((size_t)b * HW + blockIdx.x * 128 + p) * 512 + dOff + (tid & 15) * 8] =
            *(uint4*)&sW[p][(tid & 15) * 8];
    }
}

// ------------------- final: sigmoid(Wcc @ (catb*xbT)) + x, fp32 NCHW output
__global__ __launch_bounds__(256) void k_gemm_final(
        const unsigned short* __restrict__ A, const float* __restrict__ bias,
        const unsigned short* __restrict__ catb, const unsigned short* __restrict__ xbT,
        const float* __restrict__ X, float* __restrict__ OutF) {
    __shared__ unsigned short sA[128][40];
    __shared__ unsigned short sB[128][40];
    const int tid = threadIdx.x;
    const int n0 = blockIdx.x * 128;
    const int o0 = blockIdx.y * 128;
    const int b = blockIdx.z;
    const int wave = tid >> 6, lane = tid & 63, quad = lane >> 4, lr = lane & 15;
    const int m0w = (wave & 1) * 64, n0w = (wave >> 1) * 64;
    const int srow = tid >> 1, skh = (tid & 1) * 16;
    floatx4 acc[4][4] = {};

    for (int k0 = 0; k0 < 512; k0 += 32) {
        const unsigned short* ga = A + (size_t)(o0 + srow) * 512 + k0 + skh;
        uint4 a0 = *(const uint4*)(ga);
        uint4 a1 = *(const uint4*)(ga + 8);
        size_t bi = ((size_t)b * HW + n0 + srow) * 512 + k0 + skh;
        uint4 c0 = *(const uint4*)(catb + bi);
        uint4 c1 = *(const uint4*)(catb + bi + 8);
        uint4 x0 = *(const uint4*)(xbT + bi);
        uint4 x1 = *(const uint4*)(xbT + bi + 8);
        unsigned cu[8] = {c0.x, c0.y, c0.z, c0.w, c1.x, c1.y, c1.z, c1.w};
        unsigned xu[8] = {x0.x, x0.y, x0.z, x0.w, x1.x, x1.y, x1.z, x1.w};
        unsigned mu[8];
        #pragma unroll
        for (int e = 0; e < 8; ++e)
            mu[e] = pk2(lou(cu[e]) * lou(xu[e]), hiu(cu[e]) * hiu(xu[e]));
        __syncthreads();
        *(uint4*)&sA[srow][skh] = a0;
        *(uint4*)&sA[srow][skh + 8] = a1;
        uint4 m0v; m0v.x = mu[0]; m0v.y = mu[1]; m0v.z = mu[2]; m0v.w = mu[3];
        uint4 m1v; m1v.x = mu[4]; m1v.y = mu[5]; m1v.z = mu[6]; m1v.w = mu[7];
        *(uint4*)&sB[srow][skh] = m0v;
        *(uint4*)&sB[srow][skh + 8] = m1v;
        __syncthreads();
        short8 af[4], bf[4];
        #pragma unroll
        for (int i = 0; i < 4; ++i) af[i] = *(short8*)&sA[m0w + i * 16 + lr][quad * 8];
        #pragma unroll
        for (int j = 0; j < 4; ++j) bf[j] = *(short8*)&sB[n0w + j * 16 + lr][quad * 8];
        #pragma unroll
        for (int i = 0; i < 4; ++i)
            #pragma unroll
            for (int j = 0; j < 4; ++j)
                acc[i][j] = __builtin_amdgcn_mfma_f32_16x16x32_bf16(af[i], bf[j], acc[i][j], 0, 0, 0);
    }
    #pragma unroll
    for (int i = 0; i < 4; ++i) {
        float4 bs = *(const float4*)&bias[o0 + m0w + i * 16 + quad * 4];
        float bsa[4] = {bs.x, bs.y, bs.z, bs.w};
        #pragma unroll
        for (int j = 0; j < 4; ++j) {
            floatx4 v = acc[i][j];
            int pos = n0 + n0w + j * 16 + lr;
            #pragma unroll
            for (int rg = 0; rg < 4; ++rg) {
                int o = o0 + m0w + i * 16 + quad * 4 + rg;
                float f = v[rg] + bsa[rg];
                float sg = 1.f / (1.f + __expf(-f));
                size_t idx = ((size_t)b * 512 + o) * HW + pos;
                OutF[idx] = X[idx] + sg;
            }
        }
    }
}

// ------------------------------------------------------------------- launcher
extern "C" void kernel_launch(void* const* d_in, const int* in_sizes, int n_in,
                              void* d_out, int out_size, void* d_ws, size_t ws_size,
                              hipStream_t stream) {
    const float* x      = (const float*)d_in[0];
    const float* w_b1   = (const float*)d_in[1];
    const float* b_b1   = (const float*)d_in[2];
    const float* w_b21  = (const float*)d_in[3];
    const float* b_b21  = (const float*)d_in[4];
    const float* w_off2 = (const float*)d_in[5];
    const float* b_off2 = (const float*)d_in[6];
    const float* w_ddc2 = (const float*)d_in[7];
    const float* b_ddc2 = (const float*)d_in[8];
    const float* w_b31  = (const float*)d_in[9];
    const float* b_b31  = (const float*)d_in[10];
    const float* w_off3 = (const float*)d_in[11];
    const float* b_off3 = (const float*)d_in[12];
    const float* w_ddc3 = (const float*)d_in[13];
    const float* b_ddc3 = (const float*)d_in[14];
    const float* w_b4   = (const float*)d_in[15];
    const float* b_b4   = (const float*)d_in[16];
    const float* w_cc   = (const float*)d_in[17];
    const float* b_cc   = (const float*)d_in[18];

    char* wsb = (char*)d_ws;
    unsigned short* ws8  = (unsigned short*)d_ws;
    unsigned short* xbT  = (unsigned short*)(wsb + O_XBT);
    unsigned short* pxb  = (unsigned short*)(wsb + O_PXB);
    unsigned short* catb = (unsigned short*)(wsb + O_CATB);
    unsigned short* wpb  = (unsigned short*)(wsb + O_WPB);
    unsigned short* w4b  = (unsigned short*)(wsb + O_W4B);
    unsigned short* wccb = (unsigned short*)(wsb + O_WCCB);
    unsigned short* wd2t = (unsigned short*)(wsb + O_WD2T);
    unsigned short* wd3t = (unsigned short*)(wsb + O_WD3T);
    unsigned short* wo2t = (unsigned short*)(wsb + O_WO2T);
    unsigned short* wo3t = (unsigned short*)(wsb + O_WO3T);
    unsigned short* t2b  = (unsigned short*)(wsb + O_T2B);
    unsigned short* t3b  = (unsigned short*)(wsb + O_T3B);
    float* off2 = (float*)(wsb + O_OFF2);
    float* off3 = (float*)(wsb + O_OFF3);
    float* out  = (float*)d_out;

    k_prepw<<<dim3(5312), dim3(256), 0, stream>>>(
        w_b1, w_b21, w_b31, w_b4, w_cc, w_ddc2, w_ddc3, w_off2, w_off3, ws8);
    k_xpose<<<dim3(128, 16, 8), dim3(256), 0, stream>>>(x, xbT);
    k_pool<<<dim3(8192), dim3(256), 0, stream>>>(xbT, pxb);
    // b4 first (frees pxb region for t2b/t3b/offsets)
    k_gemm<<<dim3(32, 1, 8), dim3(256), 0, stream>>>(w4b, b_b4, pxb, catb, 512, 384);
    k_gemm<<<dim3(32, 1, 8), dim3(256), 0, stream>>>(wpb, b_b1, xbT, catb, 512, 0);
    k_gemm<<<dim3(32, 1, 8), dim3(256), 0, stream>>>(wpb + 128 * 512, b_b21, xbT, t2b, 128, 0);
    k_gemm<<<dim3(32, 1, 8), dim3(256), 0, stream>>>(wpb + 256 * 512, b_b31, xbT, t3b, 128, 0);
    k_offconv2<3, 18><<<dim3(32, 1, 8), dim3(512), 0, stream>>>(t2b, wo2t, b_off2, off2);
    k_offconv2<5, 50><<<dim3(32, 1, 8), dim3(512), 0, stream>>>(t3b, wo3t, b_off3, off3);
    k_deform4<3><<<dim3(32, 1, 8), dim3(512), 0, stream>>>(t2b, off2, wd2t, b_ddc2, catb, 128);
    k_deform4<5><<<dim3(32, 1, 8), dim3(512), 0, stream>>>(t3b, off3, wd3t, b_ddc3, catb, 256);
    k_gemm_final<<<dim3(32, 4, 8), dim3(256), 0, stream>>>(wccb, b_cc, catb, xbT, x, out);
}